// Round 6
// baseline (1102.885 us; speedup 1.0000x reference)
//
#include <hip/hip_runtime.h>

typedef __bf16 bf16x8 __attribute__((ext_vector_type(8)));
typedef float f32x4 __attribute__((ext_vector_type(4)));

static constexpr int Bb = 4, Ss = 2048, Ee = 1024, Hh = 16, DKk = 64, DVv = 128;
static constexpr int Mm = Bb * Ss;   // 8192
static constexpr int NQ = Hh * DKk;  // 1024
static constexpr int NV = Hh * DVv;  // 2048

#define MFMA16 __builtin_amdgcn_mfma_f32_16x16x32_bf16

#define GLL16(g, l) __builtin_amdgcn_global_load_lds(                        \
    (const __attribute__((address_space(1))) void*)(g),                      \
    (__attribute__((address_space(3))) void*)(l), 16, 0, 0)

static __device__ __forceinline__ unsigned short f2b(float f) {
  unsigned int u = __float_as_uint(f);
  u += 0x7fffu + ((u >> 16) & 1u);
  return (unsigned short)(u >> 16);
}

__global__ __launch_bounds__(256) void cast_x_kernel(const float* __restrict__ in,
                                                     unsigned short* __restrict__ out, int n4) {
  int i = blockIdx.x * 256 + threadIdx.x;
  if (i >= n4) return;
  float4 v = reinterpret_cast<const float4*>(in)[i];
  ushort4 o;
  o.x = f2b(v.x); o.y = f2b(v.y); o.z = f2b(v.z); o.w = f2b(v.w);
  reinterpret_cast<ushort4*>(out)[i] = o;
}

// in: [Bt][R][C] f32  ->  out: [Bt][C][R] bf16
__global__ __launch_bounds__(256) void transpose_cast_kernel(const float* __restrict__ in,
                                                             unsigned short* __restrict__ out,
                                                             int R, int C) {
  __shared__ float tile[32][33];
  int c0 = blockIdx.x * 32, r0 = blockIdx.y * 32;
  const float* ip = in + (size_t)blockIdx.z * R * C;
  unsigned short* op = out + (size_t)blockIdx.z * R * C;
  int tx = threadIdx.x, ty = threadIdx.y;
#pragma unroll
  for (int i = 0; i < 32; i += 8)
    tile[ty + i][tx] = ip[(size_t)(r0 + ty + i) * C + (c0 + tx)];
  __syncthreads();
#pragma unroll
  for (int i = 0; i < 32; i += 8)
    op[(size_t)(c0 + ty + i) * R + (r0 + tx)] = f2b(tile[tx][ty + i]);
}

// C = A[M][K] * BT[N][K]^T + bias[N]; 128x128 tile, BK=32, 4 waves.
// OUTMODE: 1 = f32 [M][N]; 2 = bf16 Vt[B,H,DV,S]; 3 = bf16 head-major [B,H,S,64].
template <int OUTMODE>
__global__ __launch_bounds__(256) void gemm_bt_kernel(const unsigned short* __restrict__ A,
                                                      const unsigned short* __restrict__ BT,
                                                      const float* __restrict__ bias,
                                                      void* __restrict__ Cout,
                                                      int M, int N, int K) {
  __shared__ unsigned short As[128 * 32];
  __shared__ unsigned short Bs[128 * 32];
  const int tid = threadIdx.x;
  const int wave = tid >> 6, lane = tid & 63;
  const int wr = wave >> 1, wc = wave & 1;
  const int l15 = lane & 15, lq = lane >> 4;
  const int bm = blockIdx.x * 128, bn = blockIdx.y * 128;

  f32x4 acc[4][4] = {};

  const int m0c = tid >> 2;        // staging row within 64-row group
  const int kkc = (tid & 3) << 3;  // staging k-offset (elements)

  const unsigned short* ga0 = A + (size_t)(bm + m0c) * K + kkc;
  const unsigned short* ga1 = A + (size_t)(bm + 64 + m0c) * K + kkc;
  const unsigned short* gb0 = BT + (size_t)(bn + m0c) * K + kkc;
  const unsigned short* gb1 = BT + (size_t)(bn + 64 + m0c) * K + kkc;

  for (int k0 = 0; k0 < K; k0 += 32) {
    __syncthreads();  // previous tile's LDS reads complete
    GLL16(ga0 + k0, &As[(size_t)tid * 8]);
    GLL16(ga1 + k0, &As[(size_t)(tid + 256) * 8]);
    GLL16(gb0 + k0, &Bs[(size_t)tid * 8]);
    GLL16(gb1 + k0, &Bs[(size_t)(tid + 256) * 8]);
    __syncthreads();  // drains vmcnt: LDS tiles ready
    bf16x8 af[4], bfr[4];
#pragma unroll
    for (int mi = 0; mi < 4; ++mi)
      af[mi] = *reinterpret_cast<const bf16x8*>(&As[(wr * 64 + mi * 16 + l15) * 32 + (lq << 3)]);
#pragma unroll
    for (int ni = 0; ni < 4; ++ni)
      bfr[ni] = *reinterpret_cast<const bf16x8*>(&Bs[(wc * 64 + ni * 16 + l15) * 32 + (lq << 3)]);
#pragma unroll
    for (int mi = 0; mi < 4; ++mi)
#pragma unroll
      for (int ni = 0; ni < 4; ++ni)
        acc[mi][ni] = MFMA16(af[mi], bfr[ni], acc[mi][ni], 0, 0, 0);
  }
#pragma unroll
  for (int ni = 0; ni < 4; ++ni) {
    int col = bn + wc * 64 + ni * 16 + l15;
    float bs = bias[col];
#pragma unroll
    for (int mi = 0; mi < 4; ++mi) {
      int row0 = bm + wr * 64 + mi * 16 + (lq << 2);
      if (OUTMODE == 2) {
        int b_ = row0 >> 11, s0 = row0 & 2047;
        unsigned short* dst = (unsigned short*)Cout +
            ((size_t)((b_ * Hh + (col >> 7)) * DVv + (col & 127))) * Ss + s0;
        ushort4 o;
        o.x = f2b(acc[mi][ni][0] + bs);
        o.y = f2b(acc[mi][ni][1] + bs);
        o.z = f2b(acc[mi][ni][2] + bs);
        o.w = f2b(acc[mi][ni][3] + bs);
        *reinterpret_cast<ushort4*>(dst) = o;
      } else if (OUTMODE == 3) {
        int hh = col >> 6, d = col & 63;
#pragma unroll
        for (int r = 0; r < 4; ++r) {
          int row = row0 + r;
          int b_ = row >> 11, s0 = row & 2047;
          ((unsigned short*)Cout)[(((size_t)(b_ * Hh + hh) * Ss + s0) << 6) + d] =
              f2b(acc[mi][ni][r] + bs);
        }
      } else {
#pragma unroll
        for (int r = 0; r < 4; ++r)
          reinterpret_cast<float*>(Cout)[(size_t)(row0 + r) * N + col] = acc[mi][ni][r] + bs;
      }
    }
  }
}

// Barrier-free flash attention, causal. Qh/Kh: [B,H,S,64] bf16; Vt: [B,H,128,S] bf16;
// out Aw: [B,S,H*DV] bf16. 1024 blocks x 4 waves; each wave owns ONE 32-row q-block
// (heavy-first LPT). No LDS, no barriers; K/V direct from global (L2) in MFMA layout.
__global__ __launch_bounds__(256, 4) void attn6_kernel(const unsigned short* __restrict__ Qh,
                                                       const unsigned short* __restrict__ Kh,
                                                       const unsigned short* __restrict__ Vt,
                                                       unsigned short* __restrict__ Aw) {
  const int bid = blockIdx.x;
  const int xcd = bid & 7, slot = bid >> 3;     // xcd: round-robin dispatch target
  const int g = slot >> 4, ord = slot & 15;     // 16 blocks per (b,h), all one XCD
  const int bh = xcd + (g << 3);
  const int b = bh >> 4, h = bh & 15;
  const int tid = threadIdx.x, wave = tid >> 6, lane = tid & 63;
  const int l15 = lane & 15, lq = lane >> 4;
  const int qblk = 63 - (ord * 4 + wave);       // heavy-first: nt = 32 down to 1
  const float SCL = 0.125f * 1.44269504088896f; // scale * log2(e)

  const unsigned short* Qsrc = Qh + (size_t)(b * Hh + h) * Ss * DKk;
  const unsigned short* Ksrc = Kh + (size_t)(b * Hh + h) * Ss * DKk;
  const unsigned short* Vsrc = Vt + (size_t)(b * Hh + h) * (size_t)DVv * Ss;
  unsigned short* Adst = Aw + (size_t)b * Ss * NV + h * DVv;

  const int srcA = l15 + ((lq & 1) << 5);  // lane holding kv0+{0..3} pack
  const int srcB = srcA + 16;              // lane holding kv0+{4..7} pack
  const bool selhi = (lq >> 1) & 1;        // pk register select (f parity)

  union PU { unsigned u[4]; bf16x8 v; };

  const int q0 = qblk * 32;
  const int nt = (qblk >> 1) + 1;

  bf16x8 qf[2][2];
#pragma unroll
  for (int qm = 0; qm < 2; ++qm) {
    const unsigned short* qp = Qsrc + (size_t)(q0 + qm * 16 + l15) * DKk + (lq << 3);
    qf[qm][0] = *reinterpret_cast<const bf16x8*>(qp);
    qf[qm][1] = *reinterpret_cast<const bf16x8*>(qp + 32);
  }

  f32x4 accO[2][8] = {};
  float mrow[2] = {-1e30f, -1e30f}, lrow[2] = {0.f, 0.f};

  for (int kt = 0; kt < nt; ++kt) {
    const int kbase = kt * 64;
    // K fragments: A-operand rows kv=f*16+l15, k-slice kc*32+lq*8
    bf16x8 kf[2][4];
#pragma unroll
    for (int f = 0; f < 4; ++f) {
      const unsigned short* kp = Ksrc + (size_t)(kbase + f * 16 + l15) * DKk + (lq << 3);
      kf[0][f] = *reinterpret_cast<const bf16x8*>(kp);
      kf[1][f] = *reinterpret_cast<const bf16x8*>(kp + 32);
    }
    // V^T fragments: B-operand cols dv=ni*16+l15, k-slice kc2*32+lq*8
    bf16x8 vf[2][8];
#pragma unroll
    for (int ni = 0; ni < 8; ++ni) {
      const unsigned short* vp = Vsrc + (size_t)(ni * 16 + l15) * Ss + kbase + (lq << 3);
      vf[0][ni] = *reinterpret_cast<const bf16x8*>(vp);
      vf[1][ni] = *reinterpret_cast<const bf16x8*>(vp + 32);
    }
    // QK^T swapped: accS[qm][f]: row kv_local=lq*4+r, col q=l15
    f32x4 accS[2][4] = {};
    __builtin_amdgcn_s_setprio(1);
#pragma unroll
    for (int kc = 0; kc < 2; ++kc)
#pragma unroll
      for (int f = 0; f < 4; ++f) {
        accS[0][f] = MFMA16(kf[kc][f], qf[0][kc], accS[0][f], 0, 0, 0);
        accS[1][f] = MFMA16(kf[kc][f], qf[1][kc], accS[1][f], 0, 0, 0);
      }
    __builtin_amdgcn_s_setprio(0);

    bf16x8 pfq[2][2];
#pragma unroll
    for (int qm = 0; qm < 2; ++qm) {
      const int q0m = q0 + qm * 16;
      float pl[16];
#pragma unroll
      for (int f = 0; f < 4; ++f)
#pragma unroll
        for (int r = 0; r < 4; ++r)
          pl[f * 4 + r] = accS[qm][f][r] * SCL;
      if (kbase + 63 > q0m) {
        int qg = q0m + l15;
#pragma unroll
        for (int f = 0; f < 4; ++f)
#pragma unroll
          for (int r = 0; r < 4; ++r)
            if (kbase + f * 16 + (lq << 2) + r > qg) pl[f * 4 + r] = -1e30f;
      }
      float m0 = fmaxf(fmaxf(pl[0], pl[1]), fmaxf(pl[2], pl[3]));
      float m1 = fmaxf(fmaxf(pl[4], pl[5]), fmaxf(pl[6], pl[7]));
      float m2 = fmaxf(fmaxf(pl[8], pl[9]), fmaxf(pl[10], pl[11]));
      float m3 = fmaxf(fmaxf(pl[12], pl[13]), fmaxf(pl[14], pl[15]));
      float pmx = fmaxf(fmaxf(m0, m1), fmaxf(m2, m3));
      pmx = fmaxf(pmx, __shfl_xor(pmx, 16));
      pmx = fmaxf(pmx, __shfl_xor(pmx, 32));
      float mn = mrow[qm];
      if (!__all(pmx - mn <= 8.f)) {  // T13 defer-max
        float mnew = fmaxf(mn, pmx);
        float al = exp2f(mn - mnew);
        mrow[qm] = mnew;
        lrow[qm] *= al;
        float alr[4];
#pragma unroll
        for (int r = 0; r < 4; ++r) alr[r] = __shfl(al, (lq << 2) + r);
#pragma unroll
        for (int ni = 0; ni < 8; ++ni) {
          f32x4 o = accO[qm][ni];
          o[0] *= alr[0]; o[1] *= alr[1]; o[2] *= alr[2]; o[3] *= alr[3];
          accO[qm][ni] = o;
        }
        mn = mnew;
      }
      float rs = 0.f;
#pragma unroll
      for (int i = 0; i < 16; ++i) {
        pl[i] = exp2f(pl[i] - mn);
        rs += pl[i];
      }
      rs += __shfl_xor(rs, 16);
      rs += __shfl_xor(rs, 32);
      lrow[qm] += rs;
      // pack P to bf16 pairs: pk0[f]=kv(f*16+lq*4+{0,1}), pk1[f]=+{2,3}
      unsigned pk0[4], pk1[4];
#pragma unroll
      for (int f = 0; f < 4; ++f) {
        asm("v_cvt_pk_bf16_f32 %0, %1, %2" : "=v"(pk0[f]) : "v"(pl[f * 4 + 0]), "v"(pl[f * 4 + 1]));
        asm("v_cvt_pk_bf16_f32 %0, %1, %2" : "=v"(pk1[f]) : "v"(pl[f * 4 + 2]), "v"(pl[f * 4 + 3]));
      }
      // exchange to PV A-operand: lane needs kv = kc2*32+lq*8+{0..7}
#pragma unroll
      for (int kc2 = 0; kc2 < 2; ++kc2) {
        PU u;
        unsigned a0 = __shfl((int)pk0[2 * kc2], srcA), b0 = __shfl((int)pk0[2 * kc2 + 1], srcA);
        u.u[0] = selhi ? b0 : a0;
        unsigned a1 = __shfl((int)pk1[2 * kc2], srcA), b1 = __shfl((int)pk1[2 * kc2 + 1], srcA);
        u.u[1] = selhi ? b1 : a1;
        unsigned a2 = __shfl((int)pk0[2 * kc2], srcB), b2 = __shfl((int)pk0[2 * kc2 + 1], srcB);
        u.u[2] = selhi ? b2 : a2;
        unsigned a3 = __shfl((int)pk1[2 * kc2], srcB), b3 = __shfl((int)pk1[2 * kc2 + 1], srcB);
        u.u[3] = selhi ? b3 : a3;
        pfq[qm][kc2] = u.v;
      }
    }
    // PV: O[q][dv] += P[q][kv] * V^T[dv][kv]^T
    __builtin_amdgcn_s_setprio(1);
#pragma unroll
    for (int kc2 = 0; kc2 < 2; ++kc2)
#pragma unroll
      for (int qm = 0; qm < 2; ++qm)
#pragma unroll
        for (int ni = 0; ni < 8; ++ni)
          accO[qm][ni] = MFMA16(pfq[qm][kc2], vf[kc2][ni], accO[qm][ni], 0, 0, 0);
    __builtin_amdgcn_s_setprio(0);
  }
  // epilogue: normalize + store
#pragma unroll
  for (int qm = 0; qm < 2; ++qm) {
    float li[4];
#pragma unroll
    for (int r = 0; r < 4; ++r) li[r] = 1.f / __shfl(lrow[qm], (lq << 2) + r);
#pragma unroll
    for (int ni = 0; ni < 8; ++ni) {
      int dv = ni * 16 + l15;
#pragma unroll
      for (int r = 0; r < 4; ++r) {
        int row = q0 + qm * 16 + (lq << 2) + r;
        Adst[(size_t)row * NV + dv] = f2b(accO[qm][ni][r] * li[r]);
      }
    }
  }
}

extern "C" void kernel_launch(void* const* d_in, const int* in_sizes, int n_in,
                              void* d_out, int out_size, void* d_ws, size_t ws_size,
                              hipStream_t stream) {
  (void)in_sizes; (void)n_in; (void)out_size; (void)ws_size;
  const float* x  = (const float*)d_in[0];
  const float* Wq = (const float*)d_in[1];
  const float* bq = (const float*)d_in[2];
  const float* Wk = (const float*)d_in[3];
  const float* bk = (const float*)d_in[4];
  const float* Wv = (const float*)d_in[5];
  const float* bv = (const float*)d_in[6];
  const float* Wo = (const float*)d_in[7];
  const float* bo = (const float*)d_in[8];
  float* out = (float*)d_out;

  unsigned short* ws = (unsigned short*)d_ws;
  unsigned short* xb  = ws;                    // 8388608  (x bf16 [8192][1024])
  unsigned short* WqT = xb  + 8388608;         // 1048576  ([H*DK][E])
  unsigned short* WkT = WqT + 1048576;         // 1048576
  unsigned short* WvT = WkT + 1048576;         // 2097152  ([H*DV][E])
  unsigned short* WoT = WvT + 2097152;         // 2097152  ([E][H*DV])
  unsigned short* Qw  = WoT + 2097152;         // 8388608  ([B,H,S,64])
  unsigned short* Kw  = Qw  + 8388608;         // 8388608  ([B,H,S,64])
  unsigned short* Vtw = Kw  + 8388608;         // 16777216 ([B,H,128,S])
  unsigned short* Aw  = Vtw + 16777216;        // 16777216 ([B,S,H*DV])

  cast_x_kernel<<<dim3(8192), dim3(256), 0, stream>>>(x, xb, (Mm * Ee) / 4);

  transpose_cast_kernel<<<dim3(2, 32, 16), dim3(32, 8), 0, stream>>>(Wq, WqT, Ee, DKk);
  transpose_cast_kernel<<<dim3(2, 32, 16), dim3(32, 8), 0, stream>>>(Wk, WkT, Ee, DKk);
  transpose_cast_kernel<<<dim3(4, 32, 16), dim3(32, 8), 0, stream>>>(Wv, WvT, Ee, DVv);
  transpose_cast_kernel<<<dim3(32, 64, 1), dim3(32, 8), 0, stream>>>(Wo, WoT, NV, Ee);

  gemm_bt_kernel<3><<<dim3(64, 8),  dim3(256), 0, stream>>>(xb, WqT, bq, Qw, Mm, NQ, Ee);
  gemm_bt_kernel<3><<<dim3(64, 8),  dim3(256), 0, stream>>>(xb, WkT, bk, Kw, Mm, NQ, Ee);
  gemm_bt_kernel<2><<<dim3(64, 16), dim3(256), 0, stream>>>(xb, WvT, bv, Vtw, Mm, NV, Ee);

  attn6_kernel<<<dim3(1024), dim3(256), 0, stream>>>(Qw, Kw, Vtw, Aw);

  gemm_bt_kernel<1><<<dim3(64, 8), dim3(256), 0, stream>>>(Aw, WoT, bo, out, Mm, NQ, NV);
}

// Round 7
// 441.357 us; speedup vs baseline: 2.4988x; 2.4988x over previous
//
#include <hip/hip_runtime.h>

typedef __bf16 bf16x8 __attribute__((ext_vector_type(8)));
typedef float f32x4 __attribute__((ext_vector_type(4)));

static constexpr int Bb = 4, Ss = 2048, Ee = 1024, Hh = 16, DKk = 64, DVv = 128;
static constexpr int Mm = Bb * Ss;   // 8192
static constexpr int NQ = Hh * DKk;  // 1024
static constexpr int NV = Hh * DVv;  // 2048

#define MFMA16 __builtin_amdgcn_mfma_f32_16x16x32_bf16

#define GLL16(g, l) __builtin_amdgcn_global_load_lds(                        \
    (const __attribute__((address_space(1))) void*)(g),                      \
    (__attribute__((address_space(3))) void*)(l), 16, 0, 0)

static __device__ __forceinline__ unsigned short f2b(float f) {
  unsigned int u = __float_as_uint(f);
  u += 0x7fffu + ((u >> 16) & 1u);
  return (unsigned short)(u >> 16);
}

__global__ __launch_bounds__(256) void cast_x_kernel(const float* __restrict__ in,
                                                     unsigned short* __restrict__ out, int n4) {
  int i = blockIdx.x * 256 + threadIdx.x;
  if (i >= n4) return;
  float4 v = reinterpret_cast<const float4*>(in)[i];
  ushort4 o;
  o.x = f2b(v.x); o.y = f2b(v.y); o.z = f2b(v.z); o.w = f2b(v.w);
  reinterpret_cast<ushort4*>(out)[i] = o;
}

// in: [Bt][R][C] f32  ->  out: [Bt][C][R] bf16
__global__ __launch_bounds__(256) void transpose_cast_kernel(const float* __restrict__ in,
                                                             unsigned short* __restrict__ out,
                                                             int R, int C) {
  __shared__ float tile[32][33];
  int c0 = blockIdx.x * 32, r0 = blockIdx.y * 32;
  const float* ip = in + (size_t)blockIdx.z * R * C;
  unsigned short* op = out + (size_t)blockIdx.z * R * C;
  int tx = threadIdx.x, ty = threadIdx.y;
#pragma unroll
  for (int i = 0; i < 32; i += 8)
    tile[ty + i][tx] = ip[(size_t)(r0 + ty + i) * C + (c0 + tx)];
  __syncthreads();
#pragma unroll
  for (int i = 0; i < 32; i += 8)
    op[(size_t)(c0 + ty + i) * R + (r0 + tx)] = f2b(tile[tx][ty + i]);
}

// C = A[M][K] * BT[N][K]^T + bias[N]; 128x128 tile, BK=32, 4 waves.
// OUTMODE: 1 = f32 [M][N]; 2 = bf16 Vt[B,H,DV,S]; 3 = bf16 head-major [B,H,S,64].
template <int OUTMODE>
__global__ __launch_bounds__(256) void gemm_bt_kernel(const unsigned short* __restrict__ A,
                                                      const unsigned short* __restrict__ BT,
                                                      const float* __restrict__ bias,
                                                      void* __restrict__ Cout,
                                                      int M, int N, int K) {
  __shared__ unsigned short As[128 * 32];
  __shared__ unsigned short Bs[128 * 32];
  const int tid = threadIdx.x;
  const int wave = tid >> 6, lane = tid & 63;
  const int wr = wave >> 1, wc = wave & 1;
  const int l15 = lane & 15, lq = lane >> 4;
  const int bm = blockIdx.x * 128, bn = blockIdx.y * 128;

  f32x4 acc[4][4] = {};

  const int m0c = tid >> 2;        // staging row within 64-row group
  const int kkc = (tid & 3) << 3;  // staging k-offset (elements)

  const unsigned short* ga0 = A + (size_t)(bm + m0c) * K + kkc;
  const unsigned short* ga1 = A + (size_t)(bm + 64 + m0c) * K + kkc;
  const unsigned short* gb0 = BT + (size_t)(bn + m0c) * K + kkc;
  const unsigned short* gb1 = BT + (size_t)(bn + 64 + m0c) * K + kkc;

  for (int k0 = 0; k0 < K; k0 += 32) {
    __syncthreads();  // previous tile's LDS reads complete
    GLL16(ga0 + k0, &As[(size_t)tid * 8]);
    GLL16(ga1 + k0, &As[(size_t)(tid + 256) * 8]);
    GLL16(gb0 + k0, &Bs[(size_t)tid * 8]);
    GLL16(gb1 + k0, &Bs[(size_t)(tid + 256) * 8]);
    __syncthreads();  // drains vmcnt: LDS tiles ready
    bf16x8 af[4], bfr[4];
#pragma unroll
    for (int mi = 0; mi < 4; ++mi)
      af[mi] = *reinterpret_cast<const bf16x8*>(&As[(wr * 64 + mi * 16 + l15) * 32 + (lq << 3)]);
#pragma unroll
    for (int ni = 0; ni < 4; ++ni)
      bfr[ni] = *reinterpret_cast<const bf16x8*>(&Bs[(wc * 64 + ni * 16 + l15) * 32 + (lq << 3)]);
#pragma unroll
    for (int mi = 0; mi < 4; ++mi)
#pragma unroll
      for (int ni = 0; ni < 4; ++ni)
        acc[mi][ni] = MFMA16(af[mi], bfr[ni], acc[mi][ni], 0, 0, 0);
  }
#pragma unroll
  for (int ni = 0; ni < 4; ++ni) {
    int col = bn + wc * 64 + ni * 16 + l15;
    float bs = bias[col];
#pragma unroll
    for (int mi = 0; mi < 4; ++mi) {
      int row0 = bm + wr * 64 + mi * 16 + (lq << 2);
      if (OUTMODE == 2) {
        int b_ = row0 >> 11, s0 = row0 & 2047;
        unsigned short* dst = (unsigned short*)Cout +
            ((size_t)((b_ * Hh + (col >> 7)) * DVv + (col & 127))) * Ss + s0;
        ushort4 o;
        o.x = f2b(acc[mi][ni][0] + bs);
        o.y = f2b(acc[mi][ni][1] + bs);
        o.z = f2b(acc[mi][ni][2] + bs);
        o.w = f2b(acc[mi][ni][3] + bs);
        *reinterpret_cast<ushort4*>(dst) = o;
      } else if (OUTMODE == 3) {
        int hh = col >> 6, d = col & 63;
#pragma unroll
        for (int r = 0; r < 4; ++r) {
          int row = row0 + r;
          int b_ = row >> 11, s0 = row & 2047;
          ((unsigned short*)Cout)[(((size_t)(b_ * Hh + hh) * Ss + s0) << 6) + d] =
              f2b(acc[mi][ni][r] + bs);
        }
      } else {
#pragma unroll
        for (int r = 0; r < 4; ++r)
          reinterpret_cast<float*>(Cout)[(size_t)(row0 + r) * N + col] = acc[mi][ni][r] + bs;
      }
    }
  }
}

// Barrier-free flash attention, causal. Qh/Kh: [B,H,S,64] bf16; Vt: [B,H,128,S] bf16;
// out Aw: [B,S,H*DV] bf16. 1024 blocks x 4 waves; each wave owns ONE 32-row q-block
// (heavy-first LPT). No LDS, no barriers; K/V direct from global (L2) in MFMA layout.
// NOTE: launch bounds MUST stay (256,2): the body needs ~120 VGPR; any tighter pin
// (e.g. (256,4) -> 64-VGPR cap) causes catastrophic scratch spill (rounds 4/5/6).
__global__ __launch_bounds__(256, 2) void attn7_kernel(const unsigned short* __restrict__ Qh,
                                                       const unsigned short* __restrict__ Kh,
                                                       const unsigned short* __restrict__ Vt,
                                                       unsigned short* __restrict__ Aw) {
  const int bid = blockIdx.x;
  const int xcd = bid & 7, slot = bid >> 3;     // xcd: round-robin dispatch target
  const int g = slot >> 4, ord = slot & 15;     // 16 blocks per (b,h), all one XCD
  const int bh = xcd + (g << 3);
  const int b = bh >> 4, h = bh & 15;
  const int tid = threadIdx.x, wave = tid >> 6, lane = tid & 63;
  const int l15 = lane & 15, lq = lane >> 4;
  const int qblk = 63 - (ord * 4 + wave);       // heavy-first: nt = 32 down to 1
  const float SCL = 0.125f * 1.44269504088896f; // scale * log2(e)

  const unsigned short* Qsrc = Qh + (size_t)(b * Hh + h) * Ss * DKk;
  const unsigned short* Ksrc = Kh + (size_t)(b * Hh + h) * Ss * DKk;
  const unsigned short* Vsrc = Vt + (size_t)(b * Hh + h) * (size_t)DVv * Ss;
  unsigned short* Adst = Aw + (size_t)b * Ss * NV + h * DVv;

  const int srcA = l15 + ((lq & 1) << 5);  // lane holding kv0+{0..3} pack
  const int srcB = srcA + 16;              // lane holding kv0+{4..7} pack
  const bool selhi = (lq >> 1) & 1;        // pk register select (f parity)

  union PU { unsigned u[4]; bf16x8 v; };

  const int q0 = qblk * 32;
  const int nt = (qblk >> 1) + 1;

  bf16x8 qf[2][2];
#pragma unroll
  for (int qm = 0; qm < 2; ++qm) {
    const unsigned short* qp = Qsrc + (size_t)(q0 + qm * 16 + l15) * DKk + (lq << 3);
    qf[qm][0] = *reinterpret_cast<const bf16x8*>(qp);
    qf[qm][1] = *reinterpret_cast<const bf16x8*>(qp + 32);
  }

  f32x4 accO[2][8] = {};
  float mrow[2] = {-1e30f, -1e30f}, lrow[2] = {0.f, 0.f};

  for (int kt = 0; kt < nt; ++kt) {
    const int kbase = kt * 64;
    // K fragments: A-operand rows kv=f*16+l15, k-slice kc*32+lq*8
    bf16x8 kf[2][4];
#pragma unroll
    for (int f = 0; f < 4; ++f) {
      const unsigned short* kp = Ksrc + (size_t)(kbase + f * 16 + l15) * DKk + (lq << 3);
      kf[0][f] = *reinterpret_cast<const bf16x8*>(kp);
      kf[1][f] = *reinterpret_cast<const bf16x8*>(kp + 32);
    }
    // V^T fragments: B-operand cols dv=ni*16+l15, k-slice kc2*32+lq*8
    bf16x8 vf[2][8];
#pragma unroll
    for (int ni = 0; ni < 8; ++ni) {
      const unsigned short* vp = Vsrc + (size_t)(ni * 16 + l15) * Ss + kbase + (lq << 3);
      vf[0][ni] = *reinterpret_cast<const bf16x8*>(vp);
      vf[1][ni] = *reinterpret_cast<const bf16x8*>(vp + 32);
    }
    // QK^T swapped: accS[qm][f]: row kv_local=lq*4+r, col q=l15
    f32x4 accS[2][4] = {};
    __builtin_amdgcn_s_setprio(1);
#pragma unroll
    for (int kc = 0; kc < 2; ++kc)
#pragma unroll
      for (int f = 0; f < 4; ++f) {
        accS[0][f] = MFMA16(kf[kc][f], qf[0][kc], accS[0][f], 0, 0, 0);
        accS[1][f] = MFMA16(kf[kc][f], qf[1][kc], accS[1][f], 0, 0, 0);
      }
    __builtin_amdgcn_s_setprio(0);

    bf16x8 pfq[2][2];
#pragma unroll
    for (int qm = 0; qm < 2; ++qm) {
      const int q0m = q0 + qm * 16;
      float pl[16];
#pragma unroll
      for (int f = 0; f < 4; ++f)
#pragma unroll
        for (int r = 0; r < 4; ++r)
          pl[f * 4 + r] = accS[qm][f][r] * SCL;
      if (kbase + 63 > q0m) {
        int qg = q0m + l15;
#pragma unroll
        for (int f = 0; f < 4; ++f)
#pragma unroll
          for (int r = 0; r < 4; ++r)
            if (kbase + f * 16 + (lq << 2) + r > qg) pl[f * 4 + r] = -1e30f;
      }
      float m0 = fmaxf(fmaxf(pl[0], pl[1]), fmaxf(pl[2], pl[3]));
      float m1 = fmaxf(fmaxf(pl[4], pl[5]), fmaxf(pl[6], pl[7]));
      float m2 = fmaxf(fmaxf(pl[8], pl[9]), fmaxf(pl[10], pl[11]));
      float m3 = fmaxf(fmaxf(pl[12], pl[13]), fmaxf(pl[14], pl[15]));
      float pmx = fmaxf(fmaxf(m0, m1), fmaxf(m2, m3));
      pmx = fmaxf(pmx, __shfl_xor(pmx, 16));
      pmx = fmaxf(pmx, __shfl_xor(pmx, 32));
      float mn = mrow[qm];
      if (!__all(pmx - mn <= 8.f)) {  // T13 defer-max
        float mnew = fmaxf(mn, pmx);
        float al = exp2f(mn - mnew);
        mrow[qm] = mnew;
        lrow[qm] *= al;
        float alr[4];
#pragma unroll
        for (int r = 0; r < 4; ++r) alr[r] = __shfl(al, (lq << 2) + r);
#pragma unroll
        for (int ni = 0; ni < 8; ++ni) {
          f32x4 o = accO[qm][ni];
          o[0] *= alr[0]; o[1] *= alr[1]; o[2] *= alr[2]; o[3] *= alr[3];
          accO[qm][ni] = o;
        }
        mn = mnew;
      }
      float rs = 0.f;
#pragma unroll
      for (int i = 0; i < 16; ++i) {
        pl[i] = exp2f(pl[i] - mn);
        rs += pl[i];
      }
      rs += __shfl_xor(rs, 16);
      rs += __shfl_xor(rs, 32);
      lrow[qm] += rs;
      // pack P to bf16 pairs: pk0[f]=kv(f*16+lq*4+{0,1}), pk1[f]=+{2,3}
      unsigned pk0[4], pk1[4];
#pragma unroll
      for (int f = 0; f < 4; ++f) {
        asm("v_cvt_pk_bf16_f32 %0, %1, %2" : "=v"(pk0[f]) : "v"(pl[f * 4 + 0]), "v"(pl[f * 4 + 1]));
        asm("v_cvt_pk_bf16_f32 %0, %1, %2" : "=v"(pk1[f]) : "v"(pl[f * 4 + 2]), "v"(pl[f * 4 + 3]));
      }
      // exchange to PV A-operand: lane needs kv = kc2*32+lq*8+{0..7}
#pragma unroll
      for (int kc2 = 0; kc2 < 2; ++kc2) {
        PU u;
        unsigned a0 = __shfl((int)pk0[2 * kc2], srcA), b0 = __shfl((int)pk0[2 * kc2 + 1], srcA);
        u.u[0] = selhi ? b0 : a0;
        unsigned a1 = __shfl((int)pk1[2 * kc2], srcA), b1 = __shfl((int)pk1[2 * kc2 + 1], srcA);
        u.u[1] = selhi ? b1 : a1;
        unsigned a2 = __shfl((int)pk0[2 * kc2], srcB), b2 = __shfl((int)pk0[2 * kc2 + 1], srcB);
        u.u[2] = selhi ? b2 : a2;
        unsigned a3 = __shfl((int)pk1[2 * kc2], srcB), b3 = __shfl((int)pk1[2 * kc2 + 1], srcB);
        u.u[3] = selhi ? b3 : a3;
        pfq[qm][kc2] = u.v;
      }
    }
    // PV: O[q][dv] += P[q][kv] * V^T[dv][kv]^T
    __builtin_amdgcn_s_setprio(1);
#pragma unroll
    for (int kc2 = 0; kc2 < 2; ++kc2)
#pragma unroll
      for (int qm = 0; qm < 2; ++qm)
#pragma unroll
        for (int ni = 0; ni < 8; ++ni)
          accO[qm][ni] = MFMA16(pfq[qm][kc2], vf[kc2][ni], accO[qm][ni], 0, 0, 0);
    __builtin_amdgcn_s_setprio(0);
  }
  // epilogue: normalize + store
#pragma unroll
  for (int qm = 0; qm < 2; ++qm) {
    float li[4];
#pragma unroll
    for (int r = 0; r < 4; ++r) li[r] = 1.f / __shfl(lrow[qm], (lq << 2) + r);
#pragma unroll
    for (int ni = 0; ni < 8; ++ni) {
      int dv = ni * 16 + l15;
#pragma unroll
      for (int r = 0; r < 4; ++r) {
        int row = q0 + qm * 16 + (lq << 2) + r;
        Adst[(size_t)row * NV + dv] = f2b(accO[qm][ni][r] * li[r]);
      }
    }
  }
}

extern "C" void kernel_launch(void* const* d_in, const int* in_sizes, int n_in,
                              void* d_out, int out_size, void* d_ws, size_t ws_size,
                              hipStream_t stream) {
  (void)in_sizes; (void)n_in; (void)out_size; (void)ws_size;
  const float* x  = (const float*)d_in[0];
  const float* Wq = (const float*)d_in[1];
  const float* bq = (const float*)d_in[2];
  const float* Wk = (const float*)d_in[3];
  const float* bk = (const float*)d_in[4];
  const float* Wv = (const float*)d_in[5];
  const float* bv = (const float*)d_in[6];
  const float* Wo = (const float*)d_in[7];
  const float* bo = (const float*)d_in[8];
  float* out = (float*)d_out;

  unsigned short* ws = (unsigned short*)d_ws;
  unsigned short* xb  = ws;                    // 8388608  (x bf16 [8192][1024])
  unsigned short* WqT = xb  + 8388608;         // 1048576  ([H*DK][E])
  unsigned short* WkT = WqT + 1048576;         // 1048576
  unsigned short* WvT = WkT + 1048576;         // 2097152  ([H*DV][E])
  unsigned short* WoT = WvT + 2097152;         // 2097152  ([E][H*DV])
  unsigned short* Qw  = WoT + 2097152;         // 8388608  ([B,H,S,64])
  unsigned short* Kw  = Qw  + 8388608;         // 8388608  ([B,H,S,64])
  unsigned short* Vtw = Kw  + 8388608;         // 16777216 ([B,H,128,S])
  unsigned short* Aw  = Vtw + 16777216;        // 16777216 ([B,S,H*DV])

  cast_x_kernel<<<dim3(8192), dim3(256), 0, stream>>>(x, xb, (Mm * Ee) / 4);

  transpose_cast_kernel<<<dim3(2, 32, 16), dim3(32, 8), 0, stream>>>(Wq, WqT, Ee, DKk);
  transpose_cast_kernel<<<dim3(2, 32, 16), dim3(32, 8), 0, stream>>>(Wk, WkT, Ee, DKk);
  transpose_cast_kernel<<<dim3(4, 32, 16), dim3(32, 8), 0, stream>>>(Wv, WvT, Ee, DVv);
  transpose_cast_kernel<<<dim3(32, 64, 1), dim3(32, 8), 0, stream>>>(Wo, WoT, NV, Ee);

  gemm_bt_kernel<3><<<dim3(64, 8),  dim3(256), 0, stream>>>(xb, WqT, bq, Qw, Mm, NQ, Ee);
  gemm_bt_kernel<3><<<dim3(64, 8),  dim3(256), 0, stream>>>(xb, WkT, bk, Kw, Mm, NQ, Ee);
  gemm_bt_kernel<2><<<dim3(64, 16), dim3(256), 0, stream>>>(xb, WvT, bv, Vtw, Mm, NV, Ee);

  attn7_kernel<<<dim3(1024), dim3(256), 0, stream>>>(Qw, Kw, Vtw, Aw);

  gemm_bt_kernel<1><<<dim3(64, 8), dim3(256), 0, stream>>>(Aw, WoT, bo, out, Mm, NQ, NV);
}

// Round 8
// 378.065 us; speedup vs baseline: 2.9172x; 1.1674x over previous
//
#include <hip/hip_runtime.h>

typedef __bf16 bf16x8 __attribute__((ext_vector_type(8)));
typedef float f32x4 __attribute__((ext_vector_type(4)));

static constexpr int Bb = 4, Ss = 2048, Ee = 1024, Hh = 16, DKk = 64, DVv = 128;
static constexpr int Mm = Bb * Ss;   // 8192
static constexpr int NQ = Hh * DKk;  // 1024
static constexpr int NV = Hh * DVv;  // 2048

#define MFMA16 __builtin_amdgcn_mfma_f32_16x16x32_bf16

#define GLL16(g, l) __builtin_amdgcn_global_load_lds(                        \
    (const __attribute__((address_space(1))) void*)(g),                      \
    (__attribute__((address_space(3))) void*)(l), 16, 0, 0)

static __device__ __forceinline__ unsigned short f2b(float f) {
  unsigned int u = __float_as_uint(f);
  u += 0x7fffu + ((u >> 16) & 1u);
  return (unsigned short)(u >> 16);
}

__global__ __launch_bounds__(256) void cast_x_kernel(const float* __restrict__ in,
                                                     unsigned short* __restrict__ out, int n4) {
  int i = blockIdx.x * 256 + threadIdx.x;
  if (i >= n4) return;
  float4 v = reinterpret_cast<const float4*>(in)[i];
  ushort4 o;
  o.x = f2b(v.x); o.y = f2b(v.y); o.z = f2b(v.z); o.w = f2b(v.w);
  reinterpret_cast<ushort4*>(out)[i] = o;
}

// in: [Bt][R][C] f32  ->  out: [Bt][C][R] bf16
__global__ __launch_bounds__(256) void transpose_cast_kernel(const float* __restrict__ in,
                                                             unsigned short* __restrict__ out,
                                                             int R, int C) {
  __shared__ float tile[32][33];
  int c0 = blockIdx.x * 32, r0 = blockIdx.y * 32;
  const float* ip = in + (size_t)blockIdx.z * R * C;
  unsigned short* op = out + (size_t)blockIdx.z * R * C;
  int tx = threadIdx.x, ty = threadIdx.y;
#pragma unroll
  for (int i = 0; i < 32; i += 8)
    tile[ty + i][tx] = ip[(size_t)(r0 + ty + i) * C + (c0 + tx)];
  __syncthreads();
#pragma unroll
  for (int i = 0; i < 32; i += 8)
    op[(size_t)(c0 + ty + i) * R + (r0 + tx)] = f2b(tile[tx][ty + i]);
}

// C = A[M][K] * BT[N][K]^T + bias[N]; 128x128 tile, BK=32, 4 waves.
// OUTMODE: 1 = f32 [M][N]; 2 = bf16 Vt[B,H,DV,S]; 3 = bf16 head-major [B,H,S,64].
template <int OUTMODE>
__global__ __launch_bounds__(256) void gemm_bt_kernel(const unsigned short* __restrict__ A,
                                                      const unsigned short* __restrict__ BT,
                                                      const float* __restrict__ bias,
                                                      void* __restrict__ Cout,
                                                      int M, int N, int K) {
  __shared__ unsigned short As[128 * 32];
  __shared__ unsigned short Bs[128 * 32];
  const int tid = threadIdx.x;
  const int wave = tid >> 6, lane = tid & 63;
  const int wr = wave >> 1, wc = wave & 1;
  const int l15 = lane & 15, lq = lane >> 4;
  const int bm = blockIdx.x * 128, bn = blockIdx.y * 128;

  f32x4 acc[4][4] = {};

  const int m0c = tid >> 2;        // staging row within 64-row group
  const int kkc = (tid & 3) << 3;  // staging k-offset (elements)

  const unsigned short* ga0 = A + (size_t)(bm + m0c) * K + kkc;
  const unsigned short* ga1 = A + (size_t)(bm + 64 + m0c) * K + kkc;
  const unsigned short* gb0 = BT + (size_t)(bn + m0c) * K + kkc;
  const unsigned short* gb1 = BT + (size_t)(bn + 64 + m0c) * K + kkc;

  for (int k0 = 0; k0 < K; k0 += 32) {
    __syncthreads();  // previous tile's LDS reads complete
    GLL16(ga0 + k0, &As[(size_t)tid * 8]);
    GLL16(ga1 + k0, &As[(size_t)(tid + 256) * 8]);
    GLL16(gb0 + k0, &Bs[(size_t)tid * 8]);
    GLL16(gb1 + k0, &Bs[(size_t)(tid + 256) * 8]);
    __syncthreads();  // drains vmcnt: LDS tiles ready
    bf16x8 af[4], bfr[4];
#pragma unroll
    for (int mi = 0; mi < 4; ++mi)
      af[mi] = *reinterpret_cast<const bf16x8*>(&As[(wr * 64 + mi * 16 + l15) * 32 + (lq << 3)]);
#pragma unroll
    for (int ni = 0; ni < 4; ++ni)
      bfr[ni] = *reinterpret_cast<const bf16x8*>(&Bs[(wc * 64 + ni * 16 + l15) * 32 + (lq << 3)]);
#pragma unroll
    for (int mi = 0; mi < 4; ++mi)
#pragma unroll
      for (int ni = 0; ni < 4; ++ni)
        acc[mi][ni] = MFMA16(af[mi], bfr[ni], acc[mi][ni], 0, 0, 0);
  }
#pragma unroll
  for (int ni = 0; ni < 4; ++ni) {
    int col = bn + wc * 64 + ni * 16 + l15;
    float bs = bias[col];
#pragma unroll
    for (int mi = 0; mi < 4; ++mi) {
      int row0 = bm + wr * 64 + mi * 16 + (lq << 2);
      if (OUTMODE == 2) {
        int b_ = row0 >> 11, s0 = row0 & 2047;
        unsigned short* dst = (unsigned short*)Cout +
            ((size_t)((b_ * Hh + (col >> 7)) * DVv + (col & 127))) * Ss + s0;
        ushort4 o;
        o.x = f2b(acc[mi][ni][0] + bs);
        o.y = f2b(acc[mi][ni][1] + bs);
        o.z = f2b(acc[mi][ni][2] + bs);
        o.w = f2b(acc[mi][ni][3] + bs);
        *reinterpret_cast<ushort4*>(dst) = o;
      } else if (OUTMODE == 3) {
        int hh = col >> 6, d = col & 63;
#pragma unroll
        for (int r = 0; r < 4; ++r) {
          int row = row0 + r;
          int b_ = row >> 11, s0 = row & 2047;
          ((unsigned short*)Cout)[(((size_t)(b_ * Hh + hh) * Ss + s0) << 6) + d] =
              f2b(acc[mi][ni][r] + bs);
        }
      } else {
#pragma unroll
        for (int r = 0; r < 4; ++r)
          reinterpret_cast<float*>(Cout)[(size_t)(row0 + r) * N + col] = acc[mi][ni][r] + bs;
      }
    }
  }
}

// Flash attention, causal, kv-split. Qh/Kh: [B,H,S,64] bf16; Vt: [B,H,128,S] bf16;
// out Aw: [B,S,H*DV] bf16. 1024 blocks x 4 waves = 2 pairs; waves (2p, 2p+1) split the
// kv range of q-block pair (j, 63-j) -> every wave runs 16-17 iters (uniform).
// Partials merged via LDS at end of each phase (2 barriers/phase).
// NOTE: launch bounds MUST stay (256,2): body needs ~120 VGPR; tighter pins spill
// catastrophically (rounds 4/5/6). 4 waves/SIMD comes from VGPR<=128 + grid=1024.
__global__ __launch_bounds__(256, 2) void attn8_kernel(const unsigned short* __restrict__ Qh,
                                                       const unsigned short* __restrict__ Kh,
                                                       const unsigned short* __restrict__ Vt,
                                                       unsigned short* __restrict__ Aw) {
  __shared__ float Osh[2][32][132];  // [pair][row][dv], +4 pad -> 2-way conflicts only
  __shared__ float msh[2][32], lsh[2][32];
  const int bid = blockIdx.x;
  const int xcd = bid & 7, slot = bid >> 3;     // xcd: round-robin dispatch target
  const int g = slot >> 4, ord = slot & 15;     // 16 blocks per (b,h), all one XCD
  const int bh = xcd + (g << 3);
  const int b = bh >> 4, h = bh & 15;
  const int tid = threadIdx.x, wave = tid >> 6, lane = tid & 63;
  const int l15 = lane & 15, lq = lane >> 4;
  const int pairSel = wave >> 1, half = wave & 1;
  const int p = ord * 2 + pairSel;              // pair id 0..31 -> q-blocks (p, 63-p)
  const float SCL = 0.125f * 1.44269504088896f; // scale * log2(e)

  const unsigned short* Qsrc = Qh + (size_t)(b * Hh + h) * Ss * DKk;
  const unsigned short* Ksrc = Kh + (size_t)(b * Hh + h) * Ss * DKk;
  const unsigned short* Vsrc = Vt + (size_t)(b * Hh + h) * (size_t)DVv * Ss;
  unsigned short* Adst = Aw + (size_t)b * Ss * NV + h * DVv;

  const int srcA = l15 + ((lq & 1) << 5);  // lane holding kv0+{0..3} pack
  const int srcB = srcA + 16;              // lane holding kv0+{4..7} pack
  const bool selhi = (lq >> 1) & 1;        // pk register select (f parity)

  union PU { unsigned u[4]; bf16x8 v; };

#pragma unroll 1
  for (int ph = 0; ph < 2; ++ph) {
    const int qblk = ph ? (63 - p) : p;
    const int q0 = qblk * 32;
    const int nt = (qblk >> 1) + 1;
    const int split = nt >> 1;
    const int ks = half ? split : 0;
    const int ke = half ? nt : split;

    bf16x8 qf[2][2];
#pragma unroll
    for (int qm = 0; qm < 2; ++qm) {
      const unsigned short* qp = Qsrc + (size_t)(q0 + qm * 16 + l15) * DKk + (lq << 3);
      qf[qm][0] = *reinterpret_cast<const bf16x8*>(qp);
      qf[qm][1] = *reinterpret_cast<const bf16x8*>(qp + 32);
    }

    f32x4 accO[2][8] = {};
    float mrow[2] = {-1e30f, -1e30f}, lrow[2] = {0.f, 0.f};

    for (int kt = ks; kt < ke; ++kt) {
      const int kbase = kt * 64;
      // K fragments: A-operand rows kv=f*16+l15, k-slice kc*32+lq*8
      bf16x8 kf[2][4];
#pragma unroll
      for (int f = 0; f < 4; ++f) {
        const unsigned short* kp = Ksrc + (size_t)(kbase + f * 16 + l15) * DKk + (lq << 3);
        kf[0][f] = *reinterpret_cast<const bf16x8*>(kp);
        kf[1][f] = *reinterpret_cast<const bf16x8*>(kp + 32);
      }
      // V^T fragments: B-operand cols dv=ni*16+l15, k-slice kc2*32+lq*8
      bf16x8 vf[2][8];
#pragma unroll
      for (int ni = 0; ni < 8; ++ni) {
        const unsigned short* vp = Vsrc + (size_t)(ni * 16 + l15) * Ss + kbase + (lq << 3);
        vf[0][ni] = *reinterpret_cast<const bf16x8*>(vp);
        vf[1][ni] = *reinterpret_cast<const bf16x8*>(vp + 32);
      }
      // QK^T swapped: accS[qm][f]: row kv_local=lq*4+r, col q=l15
      f32x4 accS[2][4] = {};
      __builtin_amdgcn_s_setprio(1);
#pragma unroll
      for (int kc = 0; kc < 2; ++kc)
#pragma unroll
        for (int f = 0; f < 4; ++f) {
          accS[0][f] = MFMA16(kf[kc][f], qf[0][kc], accS[0][f], 0, 0, 0);
          accS[1][f] = MFMA16(kf[kc][f], qf[1][kc], accS[1][f], 0, 0, 0);
        }
      __builtin_amdgcn_s_setprio(0);

      bf16x8 pfq[2][2];
#pragma unroll
      for (int qm = 0; qm < 2; ++qm) {
        const int q0m = q0 + qm * 16;
        float pl[16];
#pragma unroll
        for (int f = 0; f < 4; ++f)
#pragma unroll
          for (int r = 0; r < 4; ++r)
            pl[f * 4 + r] = accS[qm][f][r] * SCL;
        if (kbase + 63 > q0m) {
          int qg = q0m + l15;
#pragma unroll
          for (int f = 0; f < 4; ++f)
#pragma unroll
            for (int r = 0; r < 4; ++r)
              if (kbase + f * 16 + (lq << 2) + r > qg) pl[f * 4 + r] = -1e30f;
        }
        float m0 = fmaxf(fmaxf(pl[0], pl[1]), fmaxf(pl[2], pl[3]));
        float m1 = fmaxf(fmaxf(pl[4], pl[5]), fmaxf(pl[6], pl[7]));
        float m2 = fmaxf(fmaxf(pl[8], pl[9]), fmaxf(pl[10], pl[11]));
        float m3 = fmaxf(fmaxf(pl[12], pl[13]), fmaxf(pl[14], pl[15]));
        float pmx = fmaxf(fmaxf(m0, m1), fmaxf(m2, m3));
        pmx = fmaxf(pmx, __shfl_xor(pmx, 16));
        pmx = fmaxf(pmx, __shfl_xor(pmx, 32));
        float mn = mrow[qm];
        if (!__all(pmx - mn <= 8.f)) {  // T13 defer-max
          float mnew = fmaxf(mn, pmx);
          float al = exp2f(mn - mnew);
          mrow[qm] = mnew;
          lrow[qm] *= al;
          float alr[4];
#pragma unroll
          for (int r = 0; r < 4; ++r) alr[r] = __shfl(al, (lq << 2) + r);
#pragma unroll
          for (int ni = 0; ni < 8; ++ni) {
            f32x4 o = accO[qm][ni];
            o[0] *= alr[0]; o[1] *= alr[1]; o[2] *= alr[2]; o[3] *= alr[3];
            accO[qm][ni] = o;
          }
          mn = mnew;
        }
        float rs = 0.f;
#pragma unroll
        for (int i = 0; i < 16; ++i) {
          pl[i] = exp2f(pl[i] - mn);
          rs += pl[i];
        }
        rs += __shfl_xor(rs, 16);
        rs += __shfl_xor(rs, 32);
        lrow[qm] += rs;
        // pack P to bf16 pairs: pk0[f]=kv(f*16+lq*4+{0,1}), pk1[f]=+{2,3}
        unsigned pk0[4], pk1[4];
#pragma unroll
        for (int f = 0; f < 4; ++f) {
          asm("v_cvt_pk_bf16_f32 %0, %1, %2" : "=v"(pk0[f]) : "v"(pl[f * 4 + 0]), "v"(pl[f * 4 + 1]));
          asm("v_cvt_pk_bf16_f32 %0, %1, %2" : "=v"(pk1[f]) : "v"(pl[f * 4 + 2]), "v"(pl[f * 4 + 3]));
        }
        // exchange to PV A-operand: lane needs kv = kc2*32+lq*8+{0..7}
#pragma unroll
        for (int kc2 = 0; kc2 < 2; ++kc2) {
          PU u;
          unsigned a0 = __shfl((int)pk0[2 * kc2], srcA), b0 = __shfl((int)pk0[2 * kc2 + 1], srcA);
          u.u[0] = selhi ? b0 : a0;
          unsigned a1 = __shfl((int)pk1[2 * kc2], srcA), b1 = __shfl((int)pk1[2 * kc2 + 1], srcA);
          u.u[1] = selhi ? b1 : a1;
          unsigned a2 = __shfl((int)pk0[2 * kc2], srcB), b2 = __shfl((int)pk0[2 * kc2 + 1], srcB);
          u.u[2] = selhi ? b2 : a2;
          unsigned a3 = __shfl((int)pk1[2 * kc2], srcB), b3 = __shfl((int)pk1[2 * kc2 + 1], srcB);
          u.u[3] = selhi ? b3 : a3;
          pfq[qm][kc2] = u.v;
        }
      }
      // PV: O[q][dv] += P[q][kv] * V^T[dv][kv]^T
      __builtin_amdgcn_s_setprio(1);
#pragma unroll
      for (int kc2 = 0; kc2 < 2; ++kc2)
#pragma unroll
        for (int qm = 0; qm < 2; ++qm)
#pragma unroll
          for (int ni = 0; ni < 8; ++ni)
            accO[qm][ni] = MFMA16(pfq[qm][kc2], vf[kc2][ni], accO[qm][ni], 0, 0, 0);
      __builtin_amdgcn_s_setprio(0);
    }

    // ---- cross-wave combine: half 1 publishes partial, half 0 merges + stores ----
    if (half) {
#pragma unroll
      for (int qm = 0; qm < 2; ++qm) {
        if (lq == 0) {
          msh[pairSel][qm * 16 + l15] = mrow[qm];
          lsh[pairSel][qm * 16 + l15] = lrow[qm];
        }
#pragma unroll
        for (int ni = 0; ni < 8; ++ni)
#pragma unroll
          for (int r = 0; r < 4; ++r)
            Osh[pairSel][qm * 16 + (lq << 2) + r][ni * 16 + l15] = accO[qm][ni][r];
      }
    }
    __syncthreads();
    if (!half) {
#pragma unroll
      for (int qm = 0; qm < 2; ++qm) {
        float s0[4], s1[4];
#pragma unroll
        for (int r = 0; r < 4; ++r) {
          int rowl = qm * 16 + (lq << 2) + r;
          float m0 = __shfl(mrow[qm], (lq << 2) + r);
          float l0 = __shfl(lrow[qm], (lq << 2) + r);
          float m1 = msh[pairSel][rowl];
          float l1 = lsh[pairSel][rowl];
          float mM = fmaxf(m0, m1);
          float a0 = exp2f(m0 - mM), a1 = exp2f(m1 - mM);
          float inv = 1.f / (a0 * l0 + a1 * l1);
          s0[r] = a0 * inv;
          s1[r] = a1 * inv;
        }
#pragma unroll
        for (int ni = 0; ni < 8; ++ni) {
          int dv = ni * 16 + l15;
#pragma unroll
          for (int r = 0; r < 4; ++r) {
            int rowl = qm * 16 + (lq << 2) + r;
            float v = accO[qm][ni][r] * s0[r] + Osh[pairSel][rowl][dv] * s1[r];
            Adst[(size_t)(q0 + rowl) * NV + dv] = f2b(v);
          }
        }
      }
    }
    __syncthreads();  // protect Osh/msh/lsh reuse in next phase
  }
}

extern "C" void kernel_launch(void* const* d_in, const int* in_sizes, int n_in,
                              void* d_out, int out_size, void* d_ws, size_t ws_size,
                              hipStream_t stream) {
  (void)in_sizes; (void)n_in; (void)out_size; (void)ws_size;
  const float* x  = (const float*)d_in[0];
  const float* Wq = (const float*)d_in[1];
  const float* bq = (const float*)d_in[2];
  const float* Wk = (const float*)d_in[3];
  const float* bk = (const float*)d_in[4];
  const float* Wv = (const float*)d_in[5];
  const float* bv = (const float*)d_in[6];
  const float* Wo = (const float*)d_in[7];
  const float* bo = (const float*)d_in[8];
  float* out = (float*)d_out;

  unsigned short* ws = (unsigned short*)d_ws;
  unsigned short* xb  = ws;                    // 8388608  (x bf16 [8192][1024])
  unsigned short* WqT = xb  + 8388608;         // 1048576  ([H*DK][E])
  unsigned short* WkT = WqT + 1048576;         // 1048576
  unsigned short* WvT = WkT + 1048576;         // 2097152  ([H*DV][E])
  unsigned short* WoT = WvT + 2097152;         // 2097152  ([E][H*DV])
  unsigned short* Qw  = WoT + 2097152;         // 8388608  ([B,H,S,64])
  unsigned short* Kw  = Qw  + 8388608;         // 8388608  ([B,H,S,64])
  unsigned short* Vtw = Kw  + 8388608;         // 16777216 ([B,H,128,S])
  unsigned short* Aw  = Vtw + 16777216;        // 16777216 ([B,S,H*DV])

  cast_x_kernel<<<dim3(8192), dim3(256), 0, stream>>>(x, xb, (Mm * Ee) / 4);

  transpose_cast_kernel<<<dim3(2, 32, 16), dim3(32, 8), 0, stream>>>(Wq, WqT, Ee, DKk);
  transpose_cast_kernel<<<dim3(2, 32, 16), dim3(32, 8), 0, stream>>>(Wk, WkT, Ee, DKk);
  transpose_cast_kernel<<<dim3(4, 32, 16), dim3(32, 8), 0, stream>>>(Wv, WvT, Ee, DVv);
  transpose_cast_kernel<<<dim3(32, 64, 1), dim3(32, 8), 0, stream>>>(Wo, WoT, NV, Ee);

  gemm_bt_kernel<3><<<dim3(64, 8),  dim3(256), 0, stream>>>(xb, WqT, bq, Qw, Mm, NQ, Ee);
  gemm_bt_kernel<3><<<dim3(64, 8),  dim3(256), 0, stream>>>(xb, WkT, bk, Kw, Mm, NQ, Ee);
  gemm_bt_kernel<2><<<dim3(64, 16), dim3(256), 0, stream>>>(xb, WvT, bv, Vtw, Mm, NV, Ee);

  attn8_kernel<<<dim3(1024), dim3(256), 0, stream>>>(Qw, Kw, Vtw, Aw);

  gemm_bt_kernel<1><<<dim3(64, 8), dim3(256), 0, stream>>>(Aw, WoT, bo, out, Mm, NQ, NV);
}

// Round 9
// 332.290 us; speedup vs baseline: 3.3190x; 1.1378x over previous
//
#include <hip/hip_runtime.h>

typedef __bf16 bf16x8 __attribute__((ext_vector_type(8)));
typedef float f32x4 __attribute__((ext_vector_type(4)));

static constexpr int Bb = 4, Ss = 2048, Ee = 1024, Hh = 16, DKk = 64, DVv = 128;
static constexpr int Mm = Bb * Ss;   // 8192
static constexpr int NQ = Hh * DKk;  // 1024
static constexpr int NV = Hh * DVv;  // 2048

#define MFMA16 __builtin_amdgcn_mfma_f32_16x16x32_bf16

#define GLL16(g, l) __builtin_amdgcn_global_load_lds(                        \
    (const __attribute__((address_space(1))) void*)(g),                      \
    (__attribute__((address_space(3))) void*)(l), 16, 0, 0)

static __device__ __forceinline__ unsigned short f2b(float f) {
  unsigned int u = __float_as_uint(f);
  u += 0x7fffu + ((u >> 16) & 1u);
  return (unsigned short)(u >> 16);
}

__global__ __launch_bounds__(256) void cast_x_kernel(const float* __restrict__ in,
                                                     unsigned short* __restrict__ out, int n4) {
  int i = blockIdx.x * 256 + threadIdx.x;
  if (i >= n4) return;
  float4 v = reinterpret_cast<const float4*>(in)[i];
  ushort4 o;
  o.x = f2b(v.x); o.y = f2b(v.y); o.z = f2b(v.z); o.w = f2b(v.w);
  reinterpret_cast<ushort4*>(out)[i] = o;
}

// in: [Bt][R][C] f32  ->  out: [Bt][C][R] bf16
__global__ __launch_bounds__(256) void transpose_cast_kernel(const float* __restrict__ in,
                                                             unsigned short* __restrict__ out,
                                                             int R, int C) {
  __shared__ float tile[32][33];
  int c0 = blockIdx.x * 32, r0 = blockIdx.y * 32;
  const float* ip = in + (size_t)blockIdx.z * R * C;
  unsigned short* op = out + (size_t)blockIdx.z * R * C;
  int tx = threadIdx.x, ty = threadIdx.y;
#pragma unroll
  for (int i = 0; i < 32; i += 8)
    tile[ty + i][tx] = ip[(size_t)(r0 + ty + i) * C + (c0 + tx)];
  __syncthreads();
#pragma unroll
  for (int i = 0; i < 32; i += 8)
    op[(size_t)(c0 + ty + i) * R + (r0 + tx)] = f2b(tile[tx][ty + i]);
}

// C = A[M][K] * BT[N][K]^T + bias[N]; 128x128 tile, BK=32, 4 waves.
// OUTMODE: 1 = f32 [M][N]; 2 = bf16 Vt[B,H,DV,S]; 3 = bf16 head-major [B,H,S,64].
template <int OUTMODE>
__global__ __launch_bounds__(256) void gemm_bt_kernel(const unsigned short* __restrict__ A,
                                                      const unsigned short* __restrict__ BT,
                                                      const float* __restrict__ bias,
                                                      void* __restrict__ Cout,
                                                      int M, int N, int K) {
  __shared__ unsigned short As[128 * 32];
  __shared__ unsigned short Bs[128 * 32];
  const int tid = threadIdx.x;
  const int wave = tid >> 6, lane = tid & 63;
  const int wr = wave >> 1, wc = wave & 1;
  const int l15 = lane & 15, lq = lane >> 4;
  const int bm = blockIdx.x * 128, bn = blockIdx.y * 128;

  f32x4 acc[4][4] = {};

  const int m0c = tid >> 2;        // staging row within 64-row group
  const int kkc = (tid & 3) << 3;  // staging k-offset (elements)

  const unsigned short* ga0 = A + (size_t)(bm + m0c) * K + kkc;
  const unsigned short* ga1 = A + (size_t)(bm + 64 + m0c) * K + kkc;
  const unsigned short* gb0 = BT + (size_t)(bn + m0c) * K + kkc;
  const unsigned short* gb1 = BT + (size_t)(bn + 64 + m0c) * K + kkc;

  for (int k0 = 0; k0 < K; k0 += 32) {
    __syncthreads();  // previous tile's LDS reads complete
    GLL16(ga0 + k0, &As[(size_t)tid * 8]);
    GLL16(ga1 + k0, &As[(size_t)(tid + 256) * 8]);
    GLL16(gb0 + k0, &Bs[(size_t)tid * 8]);
    GLL16(gb1 + k0, &Bs[(size_t)(tid + 256) * 8]);
    __syncthreads();  // drains vmcnt: LDS tiles ready
    bf16x8 af[4], bfr[4];
#pragma unroll
    for (int mi = 0; mi < 4; ++mi)
      af[mi] = *reinterpret_cast<const bf16x8*>(&As[(wr * 64 + mi * 16 + l15) * 32 + (lq << 3)]);
#pragma unroll
    for (int ni = 0; ni < 4; ++ni)
      bfr[ni] = *reinterpret_cast<const bf16x8*>(&Bs[(wc * 64 + ni * 16 + l15) * 32 + (lq << 3)]);
#pragma unroll
    for (int mi = 0; mi < 4; ++mi)
#pragma unroll
      for (int ni = 0; ni < 4; ++ni)
        acc[mi][ni] = MFMA16(af[mi], bfr[ni], acc[mi][ni], 0, 0, 0);
  }
#pragma unroll
  for (int ni = 0; ni < 4; ++ni) {
    int col = bn + wc * 64 + ni * 16 + l15;
    float bs = bias[col];
#pragma unroll
    for (int mi = 0; mi < 4; ++mi) {
      int row0 = bm + wr * 64 + mi * 16 + (lq << 2);
      if (OUTMODE == 2) {
        int b_ = row0 >> 11, s0 = row0 & 2047;
        unsigned short* dst = (unsigned short*)Cout +
            ((size_t)((b_ * Hh + (col >> 7)) * DVv + (col & 127))) * Ss + s0;
        ushort4 o;
        o.x = f2b(acc[mi][ni][0] + bs);
        o.y = f2b(acc[mi][ni][1] + bs);
        o.z = f2b(acc[mi][ni][2] + bs);
        o.w = f2b(acc[mi][ni][3] + bs);
        *reinterpret_cast<ushort4*>(dst) = o;
      } else if (OUTMODE == 3) {
        int hh = col >> 6, d = col & 63;
#pragma unroll
        for (int r = 0; r < 4; ++r) {
          int row = row0 + r;
          int b_ = row >> 11, s0 = row & 2047;
          ((unsigned short*)Cout)[(((size_t)(b_ * Hh + hh) * Ss + s0) << 6) + d] =
              f2b(acc[mi][ni][r] + bs);
        }
      } else {
#pragma unroll
        for (int r = 0; r < 4; ++r)
          reinterpret_cast<float*>(Cout)[(size_t)(row0 + r) * N + col] = acc[mi][ni][r] + bs;
      }
    }
  }
}

// Flash attention, causal, 8-wave shared-LDS staging (m214-style).
// Qh/Kh: [B,H,S,64] bf16; Vt: [B,H,128,S] bf16; out Aw: [B,S,H*DV] bf16.
// Block = 512 thr / 8 waves, owns 256 q-rows (wave w: q0w = qt*256 + w*32).
// K (64x64) + V (128x64) tiles double-buffered in LDS, staged by global_load_lds
// with XOR-chunk pre-swizzled SOURCE + swizzled READ (both-sides pattern).
// One barrier per tile; stage(t+1) issued right after it (loads fly under compute t).
// Waves past their causal range skip compute but keep staging + barriers.
// Grid 512: bids 0..255 get qt=7-q, 256..511 get qt=q -> each CU slot sums to 9 units.
__global__ __launch_bounds__(512, 1) void attn9_kernel(const unsigned short* __restrict__ Qh,
                                                       const unsigned short* __restrict__ Kh,
                                                       const unsigned short* __restrict__ Vt,
                                                       unsigned short* __restrict__ Aw) {
  __shared__ unsigned short Kb[2][64 * 64];    // [kv][d] chunks, slot c stores src chunk c^(kv&7)
  __shared__ unsigned short Vb[2][128 * 64];   // [dv][kv] chunks, slot c stores src chunk c^(dv&7)
  const int bid = blockIdx.x;
  const int phase = bid >> 8, idx = bid & 255;
  const int xcd = idx & 7, sub = idx >> 3;     // XCD affinity: all blocks of a bh on one XCD
  const int bhL = sub >> 2, q = sub & 3;
  const int bh = xcd + (bhL << 3);
  const int b = bh >> 4, h = bh & 15;
  const int qt = phase ? q : 7 - q;            // pair (7-q, q) lands on same CU slot
  const int tid = threadIdx.x, wave = tid >> 6, lane = tid & 63;
  const int l15 = lane & 15, lq = lane >> 4;
  const float SCL = 0.125f * 1.44269504088896f;  // scale * log2(e)

  const unsigned short* Qsrc = Qh + (size_t)(b * Hh + h) * Ss * DKk;
  const unsigned short* Ksrc = Kh + (size_t)(b * Hh + h) * Ss * DKk;
  const unsigned short* Vsrc = Vt + (size_t)(b * Hh + h) * (size_t)DVv * Ss;
  unsigned short* Adst = Aw + (size_t)b * Ss * NV + h * DVv;

  const int nt = (qt + 1) * 4;                 // kv tiles staged by this block
  const int q0w = qt * 256 + wave * 32;        // this wave's first q row
  const int ntw = (q0w >> 6) + 1;              // kv tiles this wave computes

  // staging geometry: thread t stages 16B chunk t of K and chunks t, t+512 of V
  const int srow = tid >> 3, sch = tid & 7;
  const int soff = ((sch ^ (srow & 7)) << 3);  // pre-swizzled source offset (elements)

  const int srcA = l15 + ((lq & 1) << 5);  // lane holding kv0+{0..3} pack
  const int srcB = srcA + 16;              // lane holding kv0+{4..7} pack
  const bool selhi = (lq >> 1) & 1;        // pk register select (f parity)
  const int rsw = (l15 & 7) << 3;          // read-side XOR base (elements): row&7 -> chunk^..

  union PU { unsigned u[4]; bf16x8 v; };

  bf16x8 qf[2][2];
#pragma unroll
  for (int qm = 0; qm < 2; ++qm) {
    const unsigned short* qp = Qsrc + (size_t)(q0w + qm * 16 + l15) * DKk + (lq << 3);
    qf[qm][0] = *reinterpret_cast<const bf16x8*>(qp);
    qf[qm][1] = *reinterpret_cast<const bf16x8*>(qp + 32);
  }

  f32x4 accO[2][8] = {};
  float mrow[2] = {-1e30f, -1e30f}, lrow[2] = {0.f, 0.f};

  // prologue: stage tile 0 into buf 0
  {
    GLL16(Ksrc + (size_t)srow * DKk + soff, &Kb[0][(size_t)tid * 8]);
    GLL16(Vsrc + (size_t)srow * Ss + soff, &Vb[0][(size_t)tid * 8]);
    GLL16(Vsrc + (size_t)(srow + 64) * Ss + soff, &Vb[0][(size_t)(tid + 512) * 8]);
  }

  for (int kt = 0; kt < nt; ++kt) {
    const int kbase = kt * 64;
    const int cur = kt & 1;
    __syncthreads();  // drains stage(kt) loads; prior tile's LDS reads done
    if (kt + 1 < nt) {
      const int nb = kbase + 64;
      const int nxt = cur ^ 1;
      GLL16(Ksrc + (size_t)(nb + srow) * DKk + soff, &Kb[nxt][(size_t)tid * 8]);
      GLL16(Vsrc + (size_t)srow * Ss + nb + soff, &Vb[nxt][(size_t)tid * 8]);
      GLL16(Vsrc + (size_t)(srow + 64) * Ss + nb + soff, &Vb[nxt][(size_t)(tid + 512) * 8]);
    }
    if (kbase > q0w + 31) continue;  // causal: this wave done computing; keep staging+barriers

    // K fragments from LDS: row kv=f*16+l15, want chunk kc*4+lq -> slot ^(row&7)
    bf16x8 kf[2][4];
#pragma unroll
    for (int f = 0; f < 4; ++f) {
      const unsigned short* kr = &Kb[cur][(f * 16 + l15) * 64];
      kf[0][f] = *reinterpret_cast<const bf16x8*>(kr + (((lq << 3)) ^ rsw));
      kf[1][f] = *reinterpret_cast<const bf16x8*>(kr + ((32 + (lq << 3)) ^ rsw));
    }
    // QK^T swapped: accS[qm][f]: row kv_local=lq*4+r, col q=l15
    f32x4 accS[2][4] = {};
    __builtin_amdgcn_s_setprio(1);
#pragma unroll
    for (int kc = 0; kc < 2; ++kc)
#pragma unroll
      for (int f = 0; f < 4; ++f) {
        accS[0][f] = MFMA16(kf[kc][f], qf[0][kc], accS[0][f], 0, 0, 0);
        accS[1][f] = MFMA16(kf[kc][f], qf[1][kc], accS[1][f], 0, 0, 0);
      }
    __builtin_amdgcn_s_setprio(0);

    bf16x8 pfq[2][2];
#pragma unroll
    for (int qm = 0; qm < 2; ++qm) {
      const int q0m = q0w + qm * 16;
      float pl[16];
#pragma unroll
      for (int f = 0; f < 4; ++f)
#pragma unroll
        for (int r = 0; r < 4; ++r)
          pl[f * 4 + r] = accS[qm][f][r] * SCL;
      if (kbase + 63 > q0m) {
        int qg = q0m + l15;
#pragma unroll
        for (int f = 0; f < 4; ++f)
#pragma unroll
          for (int r = 0; r < 4; ++r)
            if (kbase + f * 16 + (lq << 2) + r > qg) pl[f * 4 + r] = -1e30f;
      }
      float m0 = fmaxf(fmaxf(pl[0], pl[1]), fmaxf(pl[2], pl[3]));
      float m1 = fmaxf(fmaxf(pl[4], pl[5]), fmaxf(pl[6], pl[7]));
      float m2 = fmaxf(fmaxf(pl[8], pl[9]), fmaxf(pl[10], pl[11]));
      float m3 = fmaxf(fmaxf(pl[12], pl[13]), fmaxf(pl[14], pl[15]));
      float pmx = fmaxf(fmaxf(m0, m1), fmaxf(m2, m3));
      pmx = fmaxf(pmx, __shfl_xor(pmx, 16));
      pmx = fmaxf(pmx, __shfl_xor(pmx, 32));
      float mn = mrow[qm];
      if (!__all(pmx - mn <= 8.f)) {  // T13 defer-max
        float mnew = fmaxf(mn, pmx);
        float al = exp2f(mn - mnew);
        mrow[qm] = mnew;
        lrow[qm] *= al;
        float alr[4];
#pragma unroll
        for (int r = 0; r < 4; ++r) alr[r] = __shfl(al, (lq << 2) + r);
#pragma unroll
        for (int ni = 0; ni < 8; ++ni) {
          f32x4 o = accO[qm][ni];
          o[0] *= alr[0]; o[1] *= alr[1]; o[2] *= alr[2]; o[3] *= alr[3];
          accO[qm][ni] = o;
        }
        mn = mnew;
      }
      float rs = 0.f;
#pragma unroll
      for (int i = 0; i < 16; ++i) {
        pl[i] = exp2f(pl[i] - mn);
        rs += pl[i];
      }
      rs += __shfl_xor(rs, 16);
      rs += __shfl_xor(rs, 32);
      lrow[qm] += rs;
      // pack P to bf16 pairs: pk0[f]=kv(f*16+lq*4+{0,1}), pk1[f]=+{2,3}
      unsigned pk0[4], pk1[4];
#pragma unroll
      for (int f = 0; f < 4; ++f) {
        asm("v_cvt_pk_bf16_f32 %0, %1, %2" : "=v"(pk0[f]) : "v"(pl[f * 4 + 0]), "v"(pl[f * 4 + 1]));
        asm("v_cvt_pk_bf16_f32 %0, %1, %2" : "=v"(pk1[f]) : "v"(pl[f * 4 + 2]), "v"(pl[f * 4 + 3]));
      }
      // exchange to PV A-operand: lane needs kv = kc2*32+lq*8+{0..7}
#pragma unroll
      for (int kc2 = 0; kc2 < 2; ++kc2) {
        PU u;
        unsigned a0 = __shfl((int)pk0[2 * kc2], srcA), b0 = __shfl((int)pk0[2 * kc2 + 1], srcA);
        u.u[0] = selhi ? b0 : a0;
        unsigned a1 = __shfl((int)pk1[2 * kc2], srcA), b1 = __shfl((int)pk1[2 * kc2 + 1], srcA);
        u.u[1] = selhi ? b1 : a1;
        unsigned a2 = __shfl((int)pk0[2 * kc2], srcB), b2 = __shfl((int)pk0[2 * kc2 + 1], srcB);
        u.u[2] = selhi ? b2 : a2;
        unsigned a3 = __shfl((int)pk1[2 * kc2], srcB), b3 = __shfl((int)pk1[2 * kc2 + 1], srcB);
        u.u[3] = selhi ? b3 : a3;
        pfq[qm][kc2] = u.v;
      }
    }
    // PV: O[q][dv] += P[q][kv] * V^T[dv][kv]^T ; V fragments from LDS just-in-time
    __builtin_amdgcn_s_setprio(1);
#pragma unroll
    for (int kc2 = 0; kc2 < 2; ++kc2) {
      bf16x8 vf[8];
#pragma unroll
      for (int ni = 0; ni < 8; ++ni) {
        const unsigned short* vr = &Vb[cur][(ni * 16 + l15) * 64];
        vf[ni] = *reinterpret_cast<const bf16x8*>(vr + (((kc2 << 5) + (lq << 3)) ^ rsw));
      }
#pragma unroll
      for (int qm = 0; qm < 2; ++qm)
#pragma unroll
        for (int ni = 0; ni < 8; ++ni)
          accO[qm][ni] = MFMA16(pfq[qm][kc2], vf[ni], accO[qm][ni], 0, 0, 0);
    }
    __builtin_amdgcn_s_setprio(0);
  }
  // epilogue: normalize + store (each wave owns its 32 rows)
#pragma unroll
  for (int qm = 0; qm < 2; ++qm) {
    float li[4];
#pragma unroll
    for (int r = 0; r < 4; ++r) li[r] = 1.f / __shfl(lrow[qm], (lq << 2) + r);
#pragma unroll
    for (int ni = 0; ni < 8; ++ni) {
      int dv = ni * 16 + l15;
#pragma unroll
      for (int r = 0; r < 4; ++r) {
        int row = q0w + qm * 16 + (lq << 2) + r;
        Adst[(size_t)row * NV + dv] = f2b(accO[qm][ni][r] * li[r]);
      }
    }
  }
}

extern "C" void kernel_launch(void* const* d_in, const int* in_sizes, int n_in,
                              void* d_out, int out_size, void* d_ws, size_t ws_size,
                              hipStream_t stream) {
  (void)in_sizes; (void)n_in; (void)out_size; (void)ws_size;
  const float* x  = (const float*)d_in[0];
  const float* Wq = (const float*)d_in[1];
  const float* bq = (const float*)d_in[2];
  const float* Wk = (const float*)d_in[3];
  const float* bk = (const float*)d_in[4];
  const float* Wv = (const float*)d_in[5];
  const float* bv = (const float*)d_in[6];
  const float* Wo = (const float*)d_in[7];
  const float* bo = (const float*)d_in[8];
  float* out = (float*)d_out;

  unsigned short* ws = (unsigned short*)d_ws;
  unsigned short* xb  = ws;                    // 8388608  (x bf16 [8192][1024])
  unsigned short* WqT = xb  + 8388608;         // 1048576  ([H*DK][E])
  unsigned short* WkT = WqT + 1048576;         // 1048576
  unsigned short* WvT = WkT + 1048576;         // 2097152  ([H*DV][E])
  unsigned short* WoT = WvT + 2097152;         // 2097152  ([E][H*DV])
  unsigned short* Qw  = WoT + 2097152;         // 8388608  ([B,H,S,64])
  unsigned short* Kw  = Qw  + 8388608;         // 8388608  ([B,H,S,64])
  unsigned short* Vtw = Kw  + 8388608;         // 16777216 ([B,H,128,S])
  unsigned short* Aw  = Vtw + 16777216;        // 16777216 ([B,S,H*DV])

  cast_x_kernel<<<dim3(8192), dim3(256), 0, stream>>>(x, xb, (Mm * Ee) / 4);

  transpose_cast_kernel<<<dim3(2, 32, 16), dim3(32, 8), 0, stream>>>(Wq, WqT, Ee, DKk);
  transpose_cast_kernel<<<dim3(2, 32, 16), dim3(32, 8), 0, stream>>>(Wk, WkT, Ee, DKk);
  transpose_cast_kernel<<<dim3(4, 32, 16), dim3(32, 8), 0, stream>>>(Wv, WvT, Ee, DVv);
  transpose_cast_kernel<<<dim3(32, 64, 1), dim3(32, 8), 0, stream>>>(Wo, WoT, NV, Ee);

  gemm_bt_kernel<3><<<dim3(64, 8),  dim3(256), 0, stream>>>(xb, WqT, bq, Qw, Mm, NQ, Ee);
  gemm_bt_kernel<3><<<dim3(64, 8),  dim3(256), 0, stream>>>(xb, WkT, bk, Kw, Mm, NQ, Ee);
  gemm_bt_kernel<2><<<dim3(64, 16), dim3(256), 0, stream>>>(xb, WvT, bv, Vtw, Mm, NV, Ee);

  attn9_kernel<<<dim3(512), dim3(512), 0, stream>>>(Qw, Kw, Vtw, Aw);

  gemm_bt_kernel<1><<<dim3(64, 8), dim3(256), 0, stream>>>(Aw, WoT, bo, out, Mm, NQ, NV);
}

// Round 11
// 326.483 us; speedup vs baseline: 3.3781x; 1.0178x over previous
//
#include <hip/hip_runtime.h>

typedef __bf16 bf16x8 __attribute__((ext_vector_type(8)));
typedef float f32x4 __attribute__((ext_vector_type(4)));

static constexpr int Bb = 4, Ss = 2048, Ee = 1024, Hh = 16, DKk = 64, DVv = 128;
static constexpr int Mm = Bb * Ss;   // 8192
static constexpr int NQ = Hh * DKk;  // 1024
static constexpr int NV = Hh * DVv;  // 2048

#define MFMA16 __builtin_amdgcn_mfma_f32_16x16x32_bf16

#define GLL16(g, l) __builtin_amdgcn_global_load_lds(                        \
    (const __attribute__((address_space(1))) void*)(g),                      \
    (__attribute__((address_space(3))) void*)(l), 16, 0, 0)

#define SBAR()   asm volatile("s_barrier" ::: "memory")
#define WLGKM0() do { asm volatile("s_waitcnt lgkmcnt(0)" ::: "memory"); \
                      __builtin_amdgcn_sched_barrier(0); } while (0)
#define WVM(n)   asm volatile("s_waitcnt vmcnt(" #n ")" ::: "memory")

static __device__ __forceinline__ unsigned short f2b(float f) {
  unsigned int u = __float_as_uint(f);
  u += 0x7fffu + ((u >> 16) & 1u);
  return (unsigned short)(u >> 16);
}

__global__ __launch_bounds__(256) void cast_x_kernel(const float* __restrict__ in,
                                                     unsigned short* __restrict__ out, int n4) {
  int i = blockIdx.x * 256 + threadIdx.x;
  if (i >= n4) return;
  float4 v = reinterpret_cast<const float4*>(in)[i];
  ushort4 o;
  o.x = f2b(v.x); o.y = f2b(v.y); o.z = f2b(v.z); o.w = f2b(v.w);
  reinterpret_cast<ushort4*>(out)[i] = o;
}

// in: [Bt][R][C] f32  ->  out: [Bt][C][R] bf16
__global__ __launch_bounds__(256) void transpose_cast_kernel(const float* __restrict__ in,
                                                             unsigned short* __restrict__ out,
                                                             int R, int C) {
  __shared__ float tile[32][33];
  int c0 = blockIdx.x * 32, r0 = blockIdx.y * 32;
  const float* ip = in + (size_t)blockIdx.z * R * C;
  unsigned short* op = out + (size_t)blockIdx.z * R * C;
  int tx = threadIdx.x, ty = threadIdx.y;
#pragma unroll
  for (int i = 0; i < 32; i += 8)
    tile[ty + i][tx] = ip[(size_t)(r0 + ty + i) * C + (c0 + tx)];
  __syncthreads();
#pragma unroll
  for (int i = 0; i < 32; i += 8)
    op[(size_t)(c0 + ty + i) * R + (r0 + tx)] = f2b(tile[tx][ty + i]);
}

// ---------------------------------------------------------------------------
// Phase-pipelined GEMM: C = A[M][K] * BT[N][K]^T + bias.
// BM=256, BN=128, BK=64; 512 thr / 8 waves (4M x 2N), per-wave 64x64 (acc 4x4).
// 2 K-tiles per iteration, 4 phases x 16 MFMA. Counted vmcnt(2), raw s_barrier,
// setprio around MFMA clusters, both-sides XOR swizzle.
// Buffer choreography (per iteration it):
//   ph0: read A0(mh0)+B0(all); stage As1 <- 2it+1 (ALWAYS - it=0 too! round-10 NaN bug)
//   ph1: read A0(mh1)        ; stage Bs0 <- 2it+2 (notlast); vmcnt(2|0)
//   ph2: read A1(mh0)+B1(all); stage As0 <- 2it+2 (notlast)
//   ph3: read A1(mh1)        ; stage Bs1 <- 2it+3 (notlast); vmcnt(2)
// vmcnt ledger: ph1-end outstanding = prevBs1(2)+As1(4)+Bs0(2) -> wait(2) completes
// As1+prevBs1 before ph2 reads; ph3-end = Bs0(2)+As0(4)+Bs1(2) -> wait(2) completes
// Bs0+As0 before next ph0. Every stage lands >=1 barrier after its buffer's last read.
// OUTMODE: 1 = f32 [M][N]; 2 = bf16 Vt[B,H,DV,S]; 4 = fused QK head-major [B,H,S,64].
// ---------------------------------------------------------------------------
template <int OUTMODE>
__global__ __launch_bounds__(512, 2) void gemm8_kernel(const unsigned short* __restrict__ A,
                                                       const unsigned short* __restrict__ BT,
                                                       const float* __restrict__ bias1,
                                                       const float* __restrict__ bias2,
                                                       void* __restrict__ out1,
                                                       void* __restrict__ out2,
                                                       int N, int K) {
  __shared__ unsigned short As0[256 * 64], As1[256 * 64];
  __shared__ unsigned short Bs0[128 * 64], Bs1[128 * 64];
  const int tid = threadIdx.x, wave = tid >> 6, lane = tid & 63;
  const int wm = wave >> 1, wn = wave & 1;
  const int l15 = lane & 15, lq = lane >> 4;
  const int nwg = gridDim.x, cpx = nwg >> 3;
  const int orig = (blockIdx.x & 7) * cpx + (blockIdx.x >> 3);  // XCD-contiguous
  const int bm = (orig & 31) << 8, bn = (orig >> 5) << 7;
  const int srow = tid >> 3;
  const int ssw = (((tid & 7) ^ (srow & 7)) << 3);  // pre-swizzled source offset
  const int rsw = l15 & 7;                          // read-side XOR
  const int nIter = K >> 7;

  f32x4 acc[4][4] = {};
  bf16x8 bf[2][4];

#define LDA(ASQ, MI, KK) \
  (*reinterpret_cast<const bf16x8*>(&(ASQ)[(size_t)((wm * 64 + (MI)*16 + l15) * 64) + (((((KK)*4 + lq)) ^ rsw) << 3)]))
#define LDB(BSQ, NI, KK) \
  (*reinterpret_cast<const bf16x8*>(&(BSQ)[(size_t)((wn * 64 + (NI)*16 + l15) * 64) + (((((KK)*4 + lq)) ^ rsw) << 3)]))

  auto stA = [&](unsigned short* dst, int kt) {
#pragma unroll
    for (int k4 = 0; k4 < 4; ++k4)
      GLL16(A + (size_t)(bm + srow + k4 * 64) * K + kt * 64 + ssw,
            &dst[(size_t)(tid + k4 * 512) * 8]);
  };
  auto stB = [&](unsigned short* dst, int kt) {
#pragma unroll
    for (int k4 = 0; k4 < 2; ++k4)
      GLL16(BT + (size_t)(bn + srow + k4 * 64) * K + kt * 64 + ssw,
            &dst[(size_t)(tid + k4 * 512) * 8]);
  };

  // prologue: A0<-tile0, B0<-tile0, B1<-tile1
  stA(As0, 0);
  stB(Bs0, 0);
  stB(Bs1, 1);
  WVM(0);
  SBAR();

  for (int it = 0; it < nIter; ++it) {
    const bool notlast = (it < nIter - 1);
    // ---- ph0: q=0 mh=0 ----
    {
      bf16x8 af[2][2];
      af[0][0] = LDA(As0, 0, 0); af[0][1] = LDA(As0, 1, 0);
      af[1][0] = LDA(As0, 0, 1); af[1][1] = LDA(As0, 1, 1);
#pragma unroll
      for (int kk = 0; kk < 2; ++kk)
#pragma unroll
        for (int ni = 0; ni < 4; ++ni) bf[kk][ni] = LDB(Bs0, ni, kk);
      stA(As1, 2 * it + 1);  // ALWAYS (it=0 included) -- round-10 bug was skipping it=0
      SBAR();
      WLGKM0();
      __builtin_amdgcn_s_setprio(1);
#pragma unroll
      for (int kk = 0; kk < 2; ++kk)
#pragma unroll
        for (int i = 0; i < 2; ++i)
#pragma unroll
          for (int ni = 0; ni < 4; ++ni)
            acc[i][ni] = MFMA16(af[kk][i], bf[kk][ni], acc[i][ni], 0, 0, 0);
      __builtin_amdgcn_s_setprio(0);
      SBAR();
    }
    // ---- ph1: q=0 mh=1 ----
    {
      bf16x8 af[2][2];
      af[0][0] = LDA(As0, 2, 0); af[0][1] = LDA(As0, 3, 0);
      af[1][0] = LDA(As0, 2, 1); af[1][1] = LDA(As0, 3, 1);
      if (notlast) stB(Bs0, 2 * it + 2);
      SBAR();
      WLGKM0();
      __builtin_amdgcn_s_setprio(1);
#pragma unroll
      for (int kk = 0; kk < 2; ++kk)
#pragma unroll
        for (int i = 0; i < 2; ++i)
#pragma unroll
          for (int ni = 0; ni < 4; ++ni)
            acc[2 + i][ni] = MFMA16(af[kk][i], bf[kk][ni], acc[2 + i][ni], 0, 0, 0);
      __builtin_amdgcn_s_setprio(0);
      if (notlast) { WVM(2); } else { WVM(0); }
      SBAR();
    }
    // ---- ph2: q=1 mh=0 ----
    {
      bf16x8 af[2][2];
      af[0][0] = LDA(As1, 0, 0); af[0][1] = LDA(As1, 1, 0);
      af[1][0] = LDA(As1, 0, 1); af[1][1] = LDA(As1, 1, 1);
#pragma unroll
      for (int kk = 0; kk < 2; ++kk)
#pragma unroll
        for (int ni = 0; ni < 4; ++ni) bf[kk][ni] = LDB(Bs1, ni, kk);
      if (notlast) stA(As0, 2 * it + 2);
      SBAR();
      WLGKM0();
      __builtin_amdgcn_s_setprio(1);
#pragma unroll
      for (int kk = 0; kk < 2; ++kk)
#pragma unroll
        for (int i = 0; i < 2; ++i)
#pragma unroll
          for (int ni = 0; ni < 4; ++ni)
            acc[i][ni] = MFMA16(af[kk][i], bf[kk][ni], acc[i][ni], 0, 0, 0);
      __builtin_amdgcn_s_setprio(0);
      SBAR();
    }
    // ---- ph3: q=1 mh=1 ----
    {
      bf16x8 af[2][2];
      af[0][0] = LDA(As1, 2, 0); af[0][1] = LDA(As1, 3, 0);
      af[1][0] = LDA(As1, 2, 1); af[1][1] = LDA(As1, 3, 1);
      if (notlast) stB(Bs1, 2 * it + 3);
      SBAR();
      WLGKM0();
      __builtin_amdgcn_s_setprio(1);
#pragma unroll
      for (int kk = 0; kk < 2; ++kk)
#pragma unroll
        for (int i = 0; i < 2; ++i)
#pragma unroll
          for (int ni = 0; ni < 4; ++ni)
            acc[2 + i][ni] = MFMA16(af[kk][i], bf[kk][ni], acc[2 + i][ni], 0, 0, 0);
      __builtin_amdgcn_s_setprio(0);
      if (notlast) WVM(2);
      SBAR();
    }
  }

  // epilogue
#pragma unroll
  for (int ni = 0; ni < 4; ++ni) {
    int col = bn + wn * 64 + ni * 16 + l15;
    float bs;
    if (OUTMODE == 4)
      bs = (col < 1024) ? bias1[col] : bias2[col - 1024];
    else
      bs = bias1[col];
#pragma unroll
    for (int mi = 0; mi < 4; ++mi) {
      int row0 = bm + wm * 64 + mi * 16 + (lq << 2);
      if (OUTMODE == 2) {
        int b_ = row0 >> 11, s0 = row0 & 2047;
        unsigned short* dst = (unsigned short*)out1 +
            ((size_t)((b_ * Hh + (col >> 7)) * DVv + (col & 127))) * Ss + s0;
        ushort4 o;
        o.x = f2b(acc[mi][ni][0] + bs);
        o.y = f2b(acc[mi][ni][1] + bs);
        o.z = f2b(acc[mi][ni][2] + bs);
        o.w = f2b(acc[mi][ni][3] + bs);
        *reinterpret_cast<ushort4*>(dst) = o;
      } else if (OUTMODE == 4) {
        unsigned short* tgt = (unsigned short*)(col < 1024 ? out1 : out2);
        int cc = col & 1023, hh = cc >> 6, d = cc & 63;
#pragma unroll
        for (int r = 0; r < 4; ++r) {
          int row = row0 + r;
          int b_ = row >> 11, s0 = row & 2047;
          tgt[(((size_t)(b_ * Hh + hh) * Ss + s0) << 6) + d] = f2b(acc[mi][ni][r] + bs);
        }
      } else {
#pragma unroll
        for (int r = 0; r < 4; ++r)
          reinterpret_cast<float*>(out1)[(size_t)(row0 + r) * N + col] = acc[mi][ni][r] + bs;
      }
    }
  }
#undef LDA
#undef LDB
}

// Flash attention, causal, 8-wave shared-LDS staging (unchanged from round 9: 164 us).
__global__ __launch_bounds__(512, 1) void attn9_kernel(const unsigned short* __restrict__ Qh,
                                                       const unsigned short* __restrict__ Kh,
                                                       const unsigned short* __restrict__ Vt,
                                                       unsigned short* __restrict__ Aw) {
  __shared__ unsigned short Kb[2][64 * 64];
  __shared__ unsigned short Vb[2][128 * 64];
  const int bid = blockIdx.x;
  const int phase = bid >> 8, idx = bid & 255;
  const int xcd = idx & 7, sub = idx >> 3;
  const int bhL = sub >> 2, q = sub & 3;
  const int bh = xcd + (bhL << 3);
  const int b = bh >> 4, h = bh & 15;
  const int qt = phase ? q : 7 - q;
  const int tid = threadIdx.x, wave = tid >> 6, lane = tid & 63;
  const int l15 = lane & 15, lq = lane >> 4;
  const float SCL = 0.125f * 1.44269504088896f;

  const unsigned short* Qsrc = Qh + (size_t)(b * Hh + h) * Ss * DKk;
  const unsigned short* Ksrc = Kh + (size_t)(b * Hh + h) * Ss * DKk;
  const unsigned short* Vsrc = Vt + (size_t)(b * Hh + h) * (size_t)DVv * Ss;
  unsigned short* Adst = Aw + (size_t)b * Ss * NV + h * DVv;

  const int nt = (qt + 1) * 4;
  const int q0w = qt * 256 + wave * 32;

  const int srow = tid >> 3, sch = tid & 7;
  const int soff = ((sch ^ (srow & 7)) << 3);

  const int srcA = l15 + ((lq & 1) << 5);
  const int srcB = srcA + 16;
  const bool selhi = (lq >> 1) & 1;
  const int rsw = (l15 & 7) << 3;

  union PU { unsigned u[4]; bf16x8 v; };

  bf16x8 qf[2][2];
#pragma unroll
  for (int qm = 0; qm < 2; ++qm) {
    const unsigned short* qp = Qsrc + (size_t)(q0w + qm * 16 + l15) * DKk + (lq << 3);
    qf[qm][0] = *reinterpret_cast<const bf16x8*>(qp);
    qf[qm][1] = *reinterpret_cast<const bf16x8*>(qp + 32);
  }

  f32x4 accO[2][8] = {};
  float mrow[2] = {-1e30f, -1e30f}, lrow[2] = {0.f, 0.f};

  {
    GLL16(Ksrc + (size_t)srow * DKk + soff, &Kb[0][(size_t)tid * 8]);
    GLL16(Vsrc + (size_t)srow * Ss + soff, &Vb[0][(size_t)tid * 8]);
    GLL16(Vsrc + (size_t)(srow + 64) * Ss + soff, &Vb[0][(size_t)(tid + 512) * 8]);
  }

  for (int kt = 0; kt < nt; ++kt) {
    const int kbase = kt * 64;
    const int cur = kt & 1;
    __syncthreads();
    if (kt + 1 < nt) {
      const int nb = kbase + 64;
      const int nxt = cur ^ 1;
      GLL16(Ksrc + (size_t)(nb + srow) * DKk + soff, &Kb[nxt][(size_t)tid * 8]);
      GLL16(Vsrc + (size_t)srow * Ss + nb + soff, &Vb[nxt][(size_t)tid * 8]);
      GLL16(Vsrc + (size_t)(srow + 64) * Ss + nb + soff, &Vb[nxt][(size_t)(tid + 512) * 8]);
    }
    if (kbase > q0w + 31) continue;

    bf16x8 kf[2][4];
#pragma unroll
    for (int f = 0; f < 4; ++f) {
      const unsigned short* kr = &Kb[cur][(f * 16 + l15) * 64];
      kf[0][f] = *reinterpret_cast<const bf16x8*>(kr + (((lq << 3)) ^ rsw));
      kf[1][f] = *reinterpret_cast<const bf16x8*>(kr + ((32 + (lq << 3)) ^ rsw));
    }
    f32x4 accS[2][4] = {};
    __builtin_amdgcn_s_setprio(1);
#pragma unroll
    for (int kc = 0; kc < 2; ++kc)
#pragma unroll
      for (int f = 0; f < 4; ++f) {
        accS[0][f] = MFMA16(kf[kc][f], qf[0][kc], accS[0][f], 0, 0, 0);
        accS[1][f] = MFMA16(kf[kc][f], qf[1][kc], accS[1][f], 0, 0, 0);
      }
    __builtin_amdgcn_s_setprio(0);

    bf16x8 pfq[2][2];
#pragma unroll
    for (int qm = 0; qm < 2; ++qm) {
      const int q0m = q0w + qm * 16;
      float pl[16];
#pragma unroll
      for (int f = 0; f < 4; ++f)
#pragma unroll
        for (int r = 0; r < 4; ++r)
          pl[f * 4 + r] = accS[qm][f][r] * SCL;
      if (kbase + 63 > q0m) {
        int qg = q0m + l15;
#pragma unroll
        for (int f = 0; f < 4; ++f)
#pragma unroll
          for (int r = 0; r < 4; ++r)
            if (kbase + f * 16 + (lq << 2) + r > qg) pl[f * 4 + r] = -1e30f;
      }
      float m0 = fmaxf(fmaxf(pl[0], pl[1]), fmaxf(pl[2], pl[3]));
      float m1 = fmaxf(fmaxf(pl[4], pl[5]), fmaxf(pl[6], pl[7]));
      float m2 = fmaxf(fmaxf(pl[8], pl[9]), fmaxf(pl[10], pl[11]));
      float m3 = fmaxf(fmaxf(pl[12], pl[13]), fmaxf(pl[14], pl[15]));
      float pmx = fmaxf(fmaxf(m0, m1), fmaxf(m2, m3));
      pmx = fmaxf(pmx, __shfl_xor(pmx, 16));
      pmx = fmaxf(pmx, __shfl_xor(pmx, 32));
      float mn = mrow[qm];
      if (!__all(pmx - mn <= 8.f)) {
        float mnew = fmaxf(mn, pmx);
        float al = exp2f(mn - mnew);
        mrow[qm] = mnew;
        lrow[qm] *= al;
        float alr[4];
#pragma unroll
        for (int r = 0; r < 4; ++r) alr[r] = __shfl(al, (lq << 2) + r);
#pragma unroll
        for (int ni = 0; ni < 8; ++ni) {
          f32x4 o = accO[qm][ni];
          o[0] *= alr[0]; o[1] *= alr[1]; o[2] *= alr[2]; o[3] *= alr[3];
          accO[qm][ni] = o;
        }
        mn = mnew;
      }
      float rs = 0.f;
#pragma unroll
      for (int i = 0; i < 16; ++i) {
        pl[i] = exp2f(pl[i] - mn);
        rs += pl[i];
      }
      rs += __shfl_xor(rs, 16);
      rs += __shfl_xor(rs, 32);
      lrow[qm] += rs;
      unsigned pk0[4], pk1[4];
#pragma unroll
      for (int f = 0; f < 4; ++f) {
        asm("v_cvt_pk_bf16_f32 %0, %1, %2" : "=v"(pk0[f]) : "v"(pl[f * 4 + 0]), "v"(pl[f * 4 + 1]));
        asm("v_cvt_pk_bf16_f32 %0, %1, %2" : "=v"(pk1[f]) : "v"(pl[f * 4 + 2]), "v"(pl[f * 4 + 3]));
      }
#pragma unroll
      for (int kc2 = 0; kc2 < 2; ++kc2) {
        PU u;
        unsigned a0 = __shfl((int)pk0[2 * kc2], srcA), b0 = __shfl((int)pk0[2 * kc2 + 1], srcA);
        u.u[0] = selhi ? b0 : a0;
        unsigned a1 = __shfl((int)pk1[2 * kc2], srcA), b1 = __shfl((int)pk1[2 * kc2 + 1], srcA);
        u.u[1] = selhi ? b1 : a1;
        unsigned a2 = __shfl((int)pk0[2 * kc2], srcB), b2 = __shfl((int)pk0[2 * kc2 + 1], srcB);
        u.u[2] = selhi ? b2 : a2;
        unsigned a3 = __shfl((int)pk1[2 * kc2], srcB), b3 = __shfl((int)pk1[2 * kc2 + 1], srcB);
        u.u[3] = selhi ? b3 : a3;
        pfq[qm][kc2] = u.v;
      }
    }
    __builtin_amdgcn_s_setprio(1);
#pragma unroll
    for (int kc2 = 0; kc2 < 2; ++kc2) {
      bf16x8 vf[8];
#pragma unroll
      for (int ni = 0; ni < 8; ++ni) {
        const unsigned short* vr = &Vb[cur][(ni * 16 + l15) * 64];
        vf[ni] = *reinterpret_cast<const bf16x8*>(vr + (((kc2 << 5) + (lq << 3)) ^ rsw));
      }
#pragma unroll
      for (int qm = 0; qm < 2; ++qm)
#pragma unroll
        for (int ni = 0; ni < 8; ++ni)
          accO[qm][ni] = MFMA16(pfq[qm][kc2], vf[ni], accO[qm][ni], 0, 0, 0);
    }
    __builtin_amdgcn_s_setprio(0);
  }
#pragma unroll
  for (int qm = 0; qm < 2; ++qm) {
    float li[4];
#pragma unroll
    for (int r = 0; r < 4; ++r) li[r] = 1.f / __shfl(lrow[qm], (lq << 2) + r);
#pragma unroll
    for (int ni = 0; ni < 8; ++ni) {
      int dv = ni * 16 + l15;
#pragma unroll
      for (int r = 0; r < 4; ++r) {
        int row = q0w + qm * 16 + (lq << 2) + r;
        Adst[(size_t)row * NV + dv] = f2b(accO[qm][ni][r] * li[r]);
      }
    }
  }
}

extern "C" void kernel_launch(void* const* d_in, const int* in_sizes, int n_in,
                              void* d_out, int out_size, void* d_ws, size_t ws_size,
                              hipStream_t stream) {
  (void)in_sizes; (void)n_in; (void)out_size; (void)ws_size;
  const float* x  = (const float*)d_in[0];
  const float* Wq = (const float*)d_in[1];
  const float* bq = (const float*)d_in[2];
  const float* Wk = (const float*)d_in[3];
  const float* bk = (const float*)d_in[4];
  const float* Wv = (const float*)d_in[5];
  const float* bv = (const float*)d_in[6];
  const float* Wo = (const float*)d_in[7];
  const float* bo = (const float*)d_in[8];
  float* out = (float*)d_out;

  unsigned short* ws = (unsigned short*)d_ws;
  unsigned short* xb  = ws;                    // 8388608  (x bf16 [8192][1024])
  unsigned short* WqT = xb  + 8388608;         // 1048576  ([H*DK][E])   } contiguous ->
  unsigned short* WkT = WqT + 1048576;         // 1048576  ([H*DK][E])   } fused QK BT [2048][1024]
  unsigned short* WvT = WkT + 1048576;         // 2097152  ([H*DV][E])
  unsigned short* WoT = WvT + 2097152;         // 2097152  ([E][H*DV])
  unsigned short* Qw  = WoT + 2097152;         // 8388608  ([B,H,S,64])
  unsigned short* Kw  = Qw  + 8388608;         // 8388608  ([B,H,S,64])
  unsigned short* Vtw = Kw  + 8388608;         // 16777216 ([B,H,128,S])
  unsigned short* Aw  = Vtw + 16777216;        // 16777216 ([B,S,H*DV])

  cast_x_kernel<<<dim3(8192), dim3(256), 0, stream>>>(x, xb, (Mm * Ee) / 4);

  transpose_cast_kernel<<<dim3(2, 32, 16), dim3(32, 8), 0, stream>>>(Wq, WqT, Ee, DKk);
  transpose_cast_kernel<<<dim3(2, 32, 16), dim3(32, 8), 0, stream>>>(Wk, WkT, Ee, DKk);
  transpose_cast_kernel<<<dim3(4, 32, 16), dim3(32, 8), 0, stream>>>(Wv, WvT, Ee, DVv);
  transpose_cast_kernel<<<dim3(32, 64, 1), dim3(32, 8), 0, stream>>>(Wo, WoT, NV, Ee);

  // fused Q+K projection: N=2048 (grid 512), writes Qw and Kw head-major
  gemm8_kernel<4><<<dim3(512), dim3(512), 0, stream>>>(xb, WqT, bq, bk, Qw, Kw, 2048, Ee);
  // V projection -> Vt[B,H,DV,S]
  gemm8_kernel<2><<<dim3(512), dim3(512), 0, stream>>>(xb, WvT, bv, nullptr, Vtw, nullptr, NV, Ee);

  attn9_kernel<<<dim3(512), dim3(512), 0, stream>>>(Qw, Kw, Vtw, Aw);

  // output projection: f32 out, K=2048
  gemm8_kernel<1><<<dim3(256), dim3(512), 0, stream>>>(Aw, WoT, bo, nullptr, out, nullptr, NQ, NV);
}

// Round 12
// 321.977 us; speedup vs baseline: 3.4254x; 1.0140x over previous
//
#include <hip/hip_runtime.h>

typedef __bf16 bf16x8 __attribute__((ext_vector_type(8)));
typedef float f32x4 __attribute__((ext_vector_type(4)));

static constexpr int Bb = 4, Ss = 2048, Ee = 1024, Hh = 16, DKk = 64, DVv = 128;
static constexpr int Mm = Bb * Ss;   // 8192
static constexpr int NQ = Hh * DKk;  // 1024
static constexpr int NV = Hh * DVv;  // 2048

#define MFMA16 __builtin_amdgcn_mfma_f32_16x16x32_bf16

#define GLL16(g, l) __builtin_amdgcn_global_load_lds(                        \
    (const __attribute__((address_space(1))) void*)(g),                      \
    (__attribute__((address_space(3))) void*)(l), 16, 0, 0)

#define SBAR()   asm volatile("s_barrier" ::: "memory")
#define WLGKM0() do { asm volatile("s_waitcnt lgkmcnt(0)" ::: "memory"); \
                      __builtin_amdgcn_sched_barrier(0); } while (0)
#define WVM(n)   asm volatile("s_waitcnt vmcnt(" #n ")" ::: "memory")

static __device__ __forceinline__ unsigned short f2b(float f) {
  unsigned int u = __float_as_uint(f);
  u += 0x7fffu + ((u >> 16) & 1u);
  return (unsigned short)(u >> 16);
}

__global__ __launch_bounds__(256) void cast_x_kernel(const float* __restrict__ in,
                                                     unsigned short* __restrict__ out, int n4) {
  int i = blockIdx.x * 256 + threadIdx.x;
  if (i >= n4) return;
  float4 v = reinterpret_cast<const float4*>(in)[i];
  ushort4 o;
  o.x = f2b(v.x); o.y = f2b(v.y); o.z = f2b(v.z); o.w = f2b(v.w);
  reinterpret_cast<ushort4*>(out)[i] = o;
}

// in: [Bt][R][C] f32  ->  out: [Bt][C][R] bf16
__global__ __launch_bounds__(256) void transpose_cast_kernel(const float* __restrict__ in,
                                                             unsigned short* __restrict__ out,
                                                             int R, int C) {
  __shared__ float tile[32][33];
  int c0 = blockIdx.x * 32, r0 = blockIdx.y * 32;
  const float* ip = in + (size_t)blockIdx.z * R * C;
  unsigned short* op = out + (size_t)blockIdx.z * R * C;
  int tx = threadIdx.x, ty = threadIdx.y;
#pragma unroll
  for (int i = 0; i < 32; i += 8)
    tile[ty + i][tx] = ip[(size_t)(r0 + ty + i) * C + (c0 + tx)];
  __syncthreads();
#pragma unroll
  for (int i = 0; i < 32; i += 8)
    op[(size_t)(c0 + ty + i) * R + (r0 + tx)] = f2b(tile[tx][ty + i]);
}

// ---------------------------------------------------------------------------
// Phase-pipelined GEMM (unchanged from round 11). BM=256,BN=128,BK=64; 8 waves.
// OUTMODE: 1 = f32 [M][N]; 2 = bf16 Vt[B,H,DV,S]; 4 = fused QK head-major [B,H,S,64].
// ---------------------------------------------------------------------------
template <int OUTMODE>
__global__ __launch_bounds__(512, 2) void gemm8_kernel(const unsigned short* __restrict__ A,
                                                       const unsigned short* __restrict__ BT,
                                                       const float* __restrict__ bias1,
                                                       const float* __restrict__ bias2,
                                                       void* __restrict__ out1,
                                                       void* __restrict__ out2,
                                                       int N, int K) {
  __shared__ unsigned short As0[256 * 64], As1[256 * 64];
  __shared__ unsigned short Bs0[128 * 64], Bs1[128 * 64];
  const int tid = threadIdx.x, wave = tid >> 6, lane = tid & 63;
  const int wm = wave >> 1, wn = wave & 1;
  const int l15 = lane & 15, lq = lane >> 4;
  const int nwg = gridDim.x, cpx = nwg >> 3;
  const int orig = (blockIdx.x & 7) * cpx + (blockIdx.x >> 3);  // XCD-contiguous
  const int bm = (orig & 31) << 8, bn = (orig >> 5) << 7;
  const int srow = tid >> 3;
  const int ssw = (((tid & 7) ^ (srow & 7)) << 3);  // pre-swizzled source offset
  const int rsw = l15 & 7;                          // read-side XOR
  const int nIter = K >> 7;

  f32x4 acc[4][4] = {};
  bf16x8 bf[2][4];

#define LDA(ASQ, MI, KK) \
  (*reinterpret_cast<const bf16x8*>(&(ASQ)[(size_t)((wm * 64 + (MI)*16 + l15) * 64) + (((((KK)*4 + lq)) ^ rsw) << 3)]))
#define LDB(BSQ, NI, KK) \
  (*reinterpret_cast<const bf16x8*>(&(BSQ)[(size_t)((wn * 64 + (NI)*16 + l15) * 64) + (((((KK)*4 + lq)) ^ rsw) << 3)]))

  auto stA = [&](unsigned short* dst, int kt) {
#pragma unroll
    for (int k4 = 0; k4 < 4; ++k4)
      GLL16(A + (size_t)(bm + srow + k4 * 64) * K + kt * 64 + ssw,
            &dst[(size_t)(tid + k4 * 512) * 8]);
  };
  auto stB = [&](unsigned short* dst, int kt) {
#pragma unroll
    for (int k4 = 0; k4 < 2; ++k4)
      GLL16(BT + (size_t)(bn + srow + k4 * 64) * K + kt * 64 + ssw,
            &dst[(size_t)(tid + k4 * 512) * 8]);
  };

  // prologue: A0<-tile0, B0<-tile0, B1<-tile1
  stA(As0, 0);
  stB(Bs0, 0);
  stB(Bs1, 1);
  WVM(0);
  SBAR();

  for (int it = 0; it < nIter; ++it) {
    const bool notlast = (it < nIter - 1);
    // ---- ph0 ----
    {
      bf16x8 af[2][2];
      af[0][0] = LDA(As0, 0, 0); af[0][1] = LDA(As0, 1, 0);
      af[1][0] = LDA(As0, 0, 1); af[1][1] = LDA(As0, 1, 1);
#pragma unroll
      for (int kk = 0; kk < 2; ++kk)
#pragma unroll
        for (int ni = 0; ni < 4; ++ni) bf[kk][ni] = LDB(Bs0, ni, kk);
      stA(As1, 2 * it + 1);  // ALWAYS (round-10 NaN bug was skipping it=0)
      SBAR();
      WLGKM0();
      __builtin_amdgcn_s_setprio(1);
#pragma unroll
      for (int kk = 0; kk < 2; ++kk)
#pragma unroll
        for (int i = 0; i < 2; ++i)
#pragma unroll
          for (int ni = 0; ni < 4; ++ni)
            acc[i][ni] = MFMA16(af[kk][i], bf[kk][ni], acc[i][ni], 0, 0, 0);
      __builtin_amdgcn_s_setprio(0);
      SBAR();
    }
    // ---- ph1 ----
    {
      bf16x8 af[2][2];
      af[0][0] = LDA(As0, 2, 0); af[0][1] = LDA(As0, 3, 0);
      af[1][0] = LDA(As0, 2, 1); af[1][1] = LDA(As0, 3, 1);
      if (notlast) stB(Bs0, 2 * it + 2);
      SBAR();
      WLGKM0();
      __builtin_amdgcn_s_setprio(1);
#pragma unroll
      for (int kk = 0; kk < 2; ++kk)
#pragma unroll
        for (int i = 0; i < 2; ++i)
#pragma unroll
          for (int ni = 0; ni < 4; ++ni)
            acc[2 + i][ni] = MFMA16(af[kk][i], bf[kk][ni], acc[2 + i][ni], 0, 0, 0);
      __builtin_amdgcn_s_setprio(0);
      if (notlast) { WVM(2); } else { WVM(0); }
      SBAR();
    }
    // ---- ph2 ----
    {
      bf16x8 af[2][2];
      af[0][0] = LDA(As1, 0, 0); af[0][1] = LDA(As1, 1, 0);
      af[1][0] = LDA(As1, 0, 1); af[1][1] = LDA(As1, 1, 1);
#pragma unroll
      for (int kk = 0; kk < 2; ++kk)
#pragma unroll
        for (int ni = 0; ni < 4; ++ni) bf[kk][ni] = LDB(Bs1, ni, kk);
      if (notlast) stA(As0, 2 * it + 2);
      SBAR();
      WLGKM0();
      __builtin_amdgcn_s_setprio(1);
#pragma unroll
      for (int kk = 0; kk < 2; ++kk)
#pragma unroll
        for (int i = 0; i < 2; ++i)
#pragma unroll
          for (int ni = 0; ni < 4; ++ni)
            acc[i][ni] = MFMA16(af[kk][i], bf[kk][ni], acc[i][ni], 0, 0, 0);
      __builtin_amdgcn_s_setprio(0);
      SBAR();
    }
    // ---- ph3 ----
    {
      bf16x8 af[2][2];
      af[0][0] = LDA(As1, 2, 0); af[0][1] = LDA(As1, 3, 0);
      af[1][0] = LDA(As1, 2, 1); af[1][1] = LDA(As1, 3, 1);
      if (notlast) stB(Bs1, 2 * it + 3);
      SBAR();
      WLGKM0();
      __builtin_amdgcn_s_setprio(1);
#pragma unroll
      for (int kk = 0; kk < 2; ++kk)
#pragma unroll
        for (int i = 0; i < 2; ++i)
#pragma unroll
          for (int ni = 0; ni < 4; ++ni)
            acc[2 + i][ni] = MFMA16(af[kk][i], bf[kk][ni], acc[2 + i][ni], 0, 0, 0);
      __builtin_amdgcn_s_setprio(0);
      if (notlast) WVM(2);
      SBAR();
    }
  }

  // epilogue
#pragma unroll
  for (int ni = 0; ni < 4; ++ni) {
    int col = bn + wn * 64 + ni * 16 + l15;
    float bs;
    if (OUTMODE == 4)
      bs = (col < 1024) ? bias1[col] : bias2[col - 1024];
    else
      bs = bias1[col];
#pragma unroll
    for (int mi = 0; mi < 4; ++mi) {
      int row0 = bm + wm * 64 + mi * 16 + (lq << 2);
      if (OUTMODE == 2) {
        int b_ = row0 >> 11, s0 = row0 & 2047;
        unsigned short* dst = (unsigned short*)out1 +
            ((size_t)((b_ * Hh + (col >> 7)) * DVv + (col & 127))) * Ss + s0;
        ushort4 o;
        o.x = f2b(acc[mi][ni][0] + bs);
        o.y = f2b(acc[mi][ni][1] + bs);
        o.z = f2b(acc[mi][ni][2] + bs);
        o.w = f2b(acc[mi][ni][3] + bs);
        *reinterpret_cast<ushort4*>(dst) = o;
      } else if (OUTMODE == 4) {
        unsigned short* tgt = (unsigned short*)(col < 1024 ? out1 : out2);
        int cc = col & 1023, hh = cc >> 6, d = cc & 63;
#pragma unroll
        for (int r = 0; r < 4; ++r) {
          int row = row0 + r;
          int b_ = row >> 11, s0 = row & 2047;
          tgt[(((size_t)(b_ * Hh + hh) * Ss + s0) << 6) + d] = f2b(acc[mi][ni][r] + bs);
        }
      } else {
#pragma unroll
        for (int r = 0; r < 4; ++r)
          reinterpret_cast<float*>(out1)[(size_t)(row0 + r) * N + col] = acc[mi][ni][r] + bs;
      }
    }
  }
#undef LDA
#undef LDB
}

// Flash attention, causal, 8-wave shared-LDS staging; P routed via per-wave LDS
// (attn4 swizzle scheme) instead of 32 ds_bpermute + 16 cndmask per tile.
// LDS: Kb 16K + Vb 32K + Ps 32K = 80KB -> exactly 2 blocks/CU.
__global__ __launch_bounds__(512, 1) void attn10_kernel(const unsigned short* __restrict__ Qh,
                                                        const unsigned short* __restrict__ Kh,
                                                        const unsigned short* __restrict__ Vt,
                                                        unsigned short* __restrict__ Aw) {
  __shared__ unsigned short Kb[2][64 * 64];
  __shared__ unsigned short Vb[2][128 * 64];
  __shared__ unsigned short Ps[8][32 * 64];  // per-wave P tile, 8B-chunk swizzle ^t2
  const int bid = blockIdx.x;
  const int phase = bid >> 8, idx = bid & 255;
  const int xcd = idx & 7, sub = idx >> 3;
  const int bhL = sub >> 2, q = sub & 3;
  const int bh = xcd + (bhL << 3);
  const int b = bh >> 4, h = bh & 15;
  const int qt = phase ? q : 7 - q;
  const int tid = threadIdx.x, wave = tid >> 6, lane = tid & 63;
  const int l15 = lane & 15, lq = lane >> 4;
  const float SCL = 0.125f * 1.44269504088896f;

  const unsigned short* Qsrc = Qh + (size_t)(b * Hh + h) * Ss * DKk;
  const unsigned short* Ksrc = Kh + (size_t)(b * Hh + h) * Ss * DKk;
  const unsigned short* Vsrc = Vt + (size_t)(b * Hh + h) * (size_t)DVv * Ss;
  unsigned short* Adst = Aw + (size_t)b * Ss * NV + h * DVv;

  const int nt = (qt + 1) * 4;
  const int q0w = qt * 256 + wave * 32;

  const int srow = tid >> 3, sch = tid & 7;
  const int soff = ((sch ^ (srow & 7)) << 3);

  const int rsw = (l15 & 7) << 3;   // K/V read-side XOR (elements)
  const int t2 = (l15 & 7) << 1;    // P-chunk swizzle (8B units)

  bf16x8 qf[2][2];
#pragma unroll
  for (int qm = 0; qm < 2; ++qm) {
    const unsigned short* qp = Qsrc + (size_t)(q0w + qm * 16 + l15) * DKk + (lq << 3);
    qf[qm][0] = *reinterpret_cast<const bf16x8*>(qp);
    qf[qm][1] = *reinterpret_cast<const bf16x8*>(qp + 32);
  }

  f32x4 accO[2][8] = {};
  float mrow[2] = {-1e30f, -1e30f}, lrow[2] = {0.f, 0.f};

  {
    GLL16(Ksrc + (size_t)srow * DKk + soff, &Kb[0][(size_t)tid * 8]);
    GLL16(Vsrc + (size_t)srow * Ss + soff, &Vb[0][(size_t)tid * 8]);
    GLL16(Vsrc + (size_t)(srow + 64) * Ss + soff, &Vb[0][(size_t)(tid + 512) * 8]);
  }

  for (int kt = 0; kt < nt; ++kt) {
    const int kbase = kt * 64;
    const int cur = kt & 1;
    __syncthreads();
    if (kt + 1 < nt) {
      const int nb = kbase + 64;
      const int nxt = cur ^ 1;
      GLL16(Ksrc + (size_t)(nb + srow) * DKk + soff, &Kb[nxt][(size_t)tid * 8]);
      GLL16(Vsrc + (size_t)srow * Ss + nb + soff, &Vb[nxt][(size_t)tid * 8]);
      GLL16(Vsrc + (size_t)(srow + 64) * Ss + nb + soff, &Vb[nxt][(size_t)(tid + 512) * 8]);
    }
    if (kbase > q0w + 31) continue;

    bf16x8 kf[2][4];
#pragma unroll
    for (int f = 0; f < 4; ++f) {
      const unsigned short* kr = &Kb[cur][(f * 16 + l15) * 64];
      kf[0][f] = *reinterpret_cast<const bf16x8*>(kr + (((lq << 3)) ^ rsw));
      kf[1][f] = *reinterpret_cast<const bf16x8*>(kr + ((32 + (lq << 3)) ^ rsw));
    }
    f32x4 accS[2][4] = {};
    __builtin_amdgcn_s_setprio(1);
#pragma unroll
    for (int kc = 0; kc < 2; ++kc)
#pragma unroll
      for (int f = 0; f < 4; ++f) {
        accS[0][f] = MFMA16(kf[kc][f], qf[0][kc], accS[0][f], 0, 0, 0);
        accS[1][f] = MFMA16(kf[kc][f], qf[1][kc], accS[1][f], 0, 0, 0);
      }
    __builtin_amdgcn_s_setprio(0);

#pragma unroll
    for (int qm = 0; qm < 2; ++qm) {
      const int q0m = q0w + qm * 16;
      float pl[16];
#pragma unroll
      for (int f = 0; f < 4; ++f)
#pragma unroll
        for (int r = 0; r < 4; ++r)
          pl[f * 4 + r] = accS[qm][f][r] * SCL;
      if (kbase + 63 > q0m) {
        int qg = q0m + l15;
#pragma unroll
        for (int f = 0; f < 4; ++f)
#pragma unroll
          for (int r = 0; r < 4; ++r)
            if (kbase + f * 16 + (lq << 2) + r > qg) pl[f * 4 + r] = -1e30f;
      }
      float m0 = fmaxf(fmaxf(pl[0], pl[1]), fmaxf(pl[2], pl[3]));
      float m1 = fmaxf(fmaxf(pl[4], pl[5]), fmaxf(pl[6], pl[7]));
      float m2 = fmaxf(fmaxf(pl[8], pl[9]), fmaxf(pl[10], pl[11]));
      float m3 = fmaxf(fmaxf(pl[12], pl[13]), fmaxf(pl[14], pl[15]));
      float pmx = fmaxf(fmaxf(m0, m1), fmaxf(m2, m3));
      pmx = fmaxf(pmx, __shfl_xor(pmx, 16));
      pmx = fmaxf(pmx, __shfl_xor(pmx, 32));
      float mn = mrow[qm];
      if (!__all(pmx - mn <= 8.f)) {
        float mnew = fmaxf(mn, pmx);
        float al = exp2f(mn - mnew);
        mrow[qm] = mnew;
        lrow[qm] *= al;
        float alr[4];
#pragma unroll
        for (int r = 0; r < 4; ++r) alr[r] = __shfl(al, (lq << 2) + r);
#pragma unroll
        for (int ni = 0; ni < 8; ++ni) {
          f32x4 o = accO[qm][ni];
          o[0] *= alr[0]; o[1] *= alr[1]; o[2] *= alr[2]; o[3] *= alr[3];
          accO[qm][ni] = o;
        }
        mn = mnew;
      }
      float rs = 0.f;
#pragma unroll
      for (int i = 0; i < 16; ++i) {
        pl[i] = exp2f(pl[i] - mn);
        rs += pl[i];
      }
      rs += __shfl_xor(rs, 16);
      rs += __shfl_xor(rs, 32);
      lrow[qm] += rs;
      // P -> per-wave LDS: row prow = qm*16+l15, chunk c8 = (f*4+lq)^t2 (8B units)
      const int prow = qm * 16 + l15;
#pragma unroll
      for (int f = 0; f < 4; ++f) {
        unsigned pk0, pk1;
        asm("v_cvt_pk_bf16_f32 %0, %1, %2" : "=v"(pk0) : "v"(pl[f * 4 + 0]), "v"(pl[f * 4 + 1]));
        asm("v_cvt_pk_bf16_f32 %0, %1, %2" : "=v"(pk1) : "v"(pl[f * 4 + 2]), "v"(pl[f * 4 + 3]));
        int c8 = ((f << 2) + lq) ^ t2;
        uint2 w;
        w.x = pk0; w.y = pk1;
        *reinterpret_cast<uint2*>(&Ps[wave][prow * 64 + c8 * 4]) = w;
      }
    }
    // PV: P read back as A-operand via swizzled b128 (same-wave in-order DS, no barrier)
    __builtin_amdgcn_s_setprio(1);
#pragma unroll
    for (int kc2 = 0; kc2 < 2; ++kc2) {
      bf16x8 vf[8];
#pragma unroll
      for (int ni = 0; ni < 8; ++ni) {
        const unsigned short* vr = &Vb[cur][(ni * 16 + l15) * 64];
        vf[ni] = *reinterpret_cast<const bf16x8*>(vr + (((kc2 << 5) + (lq << 3)) ^ rsw));
      }
      const int c8r = ((kc2 << 3) + (lq << 1)) ^ t2;
#pragma unroll
      for (int qm = 0; qm < 2; ++qm) {
        const int prow = qm * 16 + l15;
        bf16x8 pf = *reinterpret_cast<const bf16x8*>(&Ps[wave][prow * 64 + c8r * 4]);
#pragma unroll
        for (int ni = 0; ni < 8; ++ni)
          accO[qm][ni] = MFMA16(pf, vf[ni], accO[qm][ni], 0, 0, 0);
      }
    }
    __builtin_amdgcn_s_setprio(0);
  }
#pragma unroll
  for (int qm = 0; qm < 2; ++qm) {
    float li[4];
#pragma unroll
    for (int r = 0; r < 4; ++r) li[r] = 1.f / __shfl(lrow[qm], (lq << 2) + r);
#pragma unroll
    for (int ni = 0; ni < 8; ++ni) {
      int dv = ni * 16 + l15;
#pragma unroll
      for (int r = 0; r < 4; ++r) {
        int row = q0w + qm * 16 + (lq << 2) + r;
        Adst[(size_t)row * NV + dv] = f2b(accO[qm][ni][r] * li[r]);
      }
    }
  }
}

extern "C" void kernel_launch(void* const* d_in, const int* in_sizes, int n_in,
                              void* d_out, int out_size, void* d_ws, size_t ws_size,
                              hipStream_t stream) {
  (void)in_sizes; (void)n_in; (void)out_size; (void)ws_size;
  const float* x  = (const float*)d_in[0];
  const float* Wq = (const float*)d_in[1];
  const float* bq = (const float*)d_in[2];
  const float* Wk = (const float*)d_in[3];
  const float* bk = (const float*)d_in[4];
  const float* Wv = (const float*)d_in[5];
  const float* bv = (const float*)d_in[6];
  const float* Wo = (const float*)d_in[7];
  const float* bo = (const float*)d_in[8];
  float* out = (float*)d_out;

  unsigned short* ws = (unsigned short*)d_ws;
  unsigned short* xb  = ws;                    // 8388608  (x bf16 [8192][1024])
  unsigned short* WqT = xb  + 8388608;         // 1048576  ([H*DK][E])   } contiguous ->
  unsigned short* WkT = WqT + 1048576;         // 1048576  ([H*DK][E])   } fused QK BT [2048][1024]
  unsigned short* WvT = WkT + 1048576;         // 2097152  ([H*DV][E])
  unsigned short* WoT = WvT + 2097152;         // 2097152  ([E][H*DV])
  unsigned short* Qw  = WoT + 2097152;         // 8388608  ([B,H,S,64])
  unsigned short* Kw  = Qw  + 8388608;         // 8388608  ([B,H,S,64])
  unsigned short* Vtw = Kw  + 8388608;         // 16777216 ([B,H,128,S])
  unsigned short* Aw  = Vtw + 16777216;        // 16777216 ([B,S,H*DV])

  cast_x_kernel<<<dim3(8192), dim3(256), 0, stream>>>(x, xb, (Mm * Ee) / 4);

  transpose_cast_kernel<<<dim3(2, 32, 16), dim3(32, 8), 0, stream>>>(Wq, WqT, Ee, DKk);
  transpose_cast_kernel<<<dim3(2, 32, 16), dim3(32, 8), 0, stream>>>(Wk, WkT, Ee, DKk);
  transpose_cast_kernel<<<dim3(4, 32, 16), dim3(32, 8), 0, stream>>>(Wv, WvT, Ee, DVv);
  transpose_cast_kernel<<<dim3(32, 64, 1), dim3(32, 8), 0, stream>>>(Wo, WoT, NV, Ee);

  // fused Q+K projection: N=2048 (grid 512), writes Qw and Kw head-major
  gemm8_kernel<4><<<dim3(512), dim3(512), 0, stream>>>(xb, WqT, bq, bk, Qw, Kw, 2048, Ee);
  // V projection -> Vt[B,H,DV,S]
  gemm8_kernel<2><<<dim3(512), dim3(512), 0, stream>>>(xb, WvT, bv, nullptr, Vtw, nullptr, NV, Ee);

  attn10_kernel<<<dim3(512), dim3(512), 0, stream>>>(Qw, Kw, Vtw, Aw);

  // output projection: f32 out, K=2048
  gemm8_kernel<1><<<dim3(256), dim3(512), 0, stream>>>(Aw, WoT, bo, nullptr, out, nullptr, NQ, NV);
}

// Round 13
// 306.315 us; speedup vs baseline: 3.6005x; 1.0511x over previous
//
#include <hip/hip_runtime.h>

typedef __bf16 bf16x8 __attribute__((ext_vector_type(8)));
typedef float f32x4 __attribute__((ext_vector_type(4)));
typedef float f32x16 __attribute__((ext_vector_type(16)));

static constexpr int Bb = 4, Ss = 2048, Ee = 1024, Hh = 16, DKk = 64, DVv = 128;
static constexpr int Mm = Bb * Ss;   // 8192
static constexpr int NQ = Hh * DKk;  // 1024
static constexpr int NV = Hh * DVv;  // 2048

#define MFMA16 __builtin_amdgcn_mfma_f32_16x16x32_bf16
#define MFMA32 __builtin_amdgcn_mfma_f32_32x32x16_bf16

#define GLL16(g, l) __builtin_amdgcn_global_load_lds(                        \
    (const __attribute__((address_space(1))) void*)(g),                      \
    (__attribute__((address_space(3))) void*)(l), 16, 0, 0)

#define SBAR()   asm volatile("s_barrier" ::: "memory")
#define WLGKM0() do { asm volatile("s_waitcnt lgkmcnt(0)" ::: "memory"); \
                      __builtin_amdgcn_sched_barrier(0); } while (0)
#define WVM(n)   asm volatile("s_waitcnt vmcnt(" #n ")" ::: "memory")

static __device__ __forceinline__ unsigned short f2b(float f) {
  unsigned int u = __float_as_uint(f);
  u += 0x7fffu + ((u >> 16) & 1u);
  return (unsigned short)(u >> 16);
}

__global__ __launch_bounds__(256) void cast_x_kernel(const float* __restrict__ in,
                                                     unsigned short* __restrict__ out, int n4) {
  int i = blockIdx.x * 256 + threadIdx.x;
  if (i >= n4) return;
  float4 v = reinterpret_cast<const float4*>(in)[i];
  ushort4 o;
  o.x = f2b(v.x); o.y = f2b(v.y); o.z = f2b(v.z); o.w = f2b(v.w);
  reinterpret_cast<ushort4*>(out)[i] = o;
}

// in: [Bt][R][C] f32  ->  out: [Bt][C][R] bf16
__global__ __launch_bounds__(256) void transpose_cast_kernel(const float* __restrict__ in,
                                                             unsigned short* __restrict__ out,
                                                             int R, int C) {
  __shared__ float tile[32][33];
  int c0 = blockIdx.x * 32, r0 = blockIdx.y * 32;
  const float* ip = in + (size_t)blockIdx.z * R * C;
  unsigned short* op = out + (size_t)blockIdx.z * R * C;
  int tx = threadIdx.x, ty = threadIdx.y;
#pragma unroll
  for (int i = 0; i < 32; i += 8)
    tile[ty + i][tx] = ip[(size_t)(r0 + ty + i) * C + (c0 + tx)];
  __syncthreads();
#pragma unroll
  for (int i = 0; i < 32; i += 8)
    op[(size_t)(c0 + ty + i) * R + (r0 + tx)] = f2b(tile[tx][ty + i]);
}

// ---------------------------------------------------------------------------
// Phase-pipelined GEMM (round-11 structure, unchanged except OUTMODE4 scales Q).
// OUTMODE: 1 = f32 [M][N]; 2 = bf16 Vt[B,H,DV,S]; 4 = fused QK head-major,
//          Q half (cols<1024) pre-scaled by 0.125*log2(e) for attn exp2 domain.
// ---------------------------------------------------------------------------
template <int OUTMODE>
__global__ __launch_bounds__(512, 2) void gemm8_kernel(const unsigned short* __restrict__ A,
                                                       const unsigned short* __restrict__ BT,
                                                       const float* __restrict__ bias1,
                                                       const float* __restrict__ bias2,
                                                       void* __restrict__ out1,
                                                       void* __restrict__ out2,
                                                       int N, int K) {
  __shared__ unsigned short As0[256 * 64], As1[256 * 64];
  __shared__ unsigned short Bs0[128 * 64], Bs1[128 * 64];
  const int tid = threadIdx.x, wave = tid >> 6, lane = tid & 63;
  const int wm = wave >> 1, wn = wave & 1;
  const int l15 = lane & 15, lq = lane >> 4;
  const int nwg = gridDim.x, cpx = nwg >> 3;
  const int orig = (blockIdx.x & 7) * cpx + (blockIdx.x >> 3);  // XCD-contiguous
  const int bm = (orig & 31) << 8, bn = (orig >> 5) << 7;
  const int srow = tid >> 3;
  const int ssw = (((tid & 7) ^ (srow & 7)) << 3);  // pre-swizzled source offset
  const int rsw = l15 & 7;                          // read-side XOR
  const int nIter = K >> 7;

  f32x4 acc[4][4] = {};
  bf16x8 bf[2][4];

#define LDA(ASQ, MI, KK) \
  (*reinterpret_cast<const bf16x8*>(&(ASQ)[(size_t)((wm * 64 + (MI)*16 + l15) * 64) + (((((KK)*4 + lq)) ^ rsw) << 3)]))
#define LDB(BSQ, NI, KK) \
  (*reinterpret_cast<const bf16x8*>(&(BSQ)[(size_t)((wn * 64 + (NI)*16 + l15) * 64) + (((((KK)*4 + lq)) ^ rsw) << 3)]))

  auto stA = [&](unsigned short* dst, int kt) {
#pragma unroll
    for (int k4 = 0; k4 < 4; ++k4)
      GLL16(A + (size_t)(bm + srow + k4 * 64) * K + kt * 64 + ssw,
            &dst[(size_t)(tid + k4 * 512) * 8]);
  };
  auto stB = [&](unsigned short* dst, int kt) {
#pragma unroll
    for (int k4 = 0; k4 < 2; ++k4)
      GLL16(BT + (size_t)(bn + srow + k4 * 64) * K + kt * 64 + ssw,
            &dst[(size_t)(tid + k4 * 512) * 8]);
  };

  stA(As0, 0);
  stB(Bs0, 0);
  stB(Bs1, 1);
  WVM(0);
  SBAR();

  for (int it = 0; it < nIter; ++it) {
    const bool notlast = (it < nIter - 1);
    // ---- ph0 ----
    {
      bf16x8 af[2][2];
      af[0][0] = LDA(As0, 0, 0); af[0][1] = LDA(As0, 1, 0);
      af[1][0] = LDA(As0, 0, 1); af[1][1] = LDA(As0, 1, 1);
#pragma unroll
      for (int kk = 0; kk < 2; ++kk)
#pragma unroll
        for (int ni = 0; ni < 4; ++ni) bf[kk][ni] = LDB(Bs0, ni, kk);
      stA(As1, 2 * it + 1);  // ALWAYS (round-10 NaN bug was skipping it=0)
      SBAR();
      WLGKM0();
      __builtin_amdgcn_s_setprio(1);
#pragma unroll
      for (int kk = 0; kk < 2; ++kk)
#pragma unroll
        for (int i = 0; i < 2; ++i)
#pragma unroll
          for (int ni = 0; ni < 4; ++ni)
            acc[i][ni] = MFMA16(af[kk][i], bf[kk][ni], acc[i][ni], 0, 0, 0);
      __builtin_amdgcn_s_setprio(0);
      SBAR();
    }
    // ---- ph1 ----
    {
      bf16x8 af[2][2];
      af[0][0] = LDA(As0, 2, 0); af[0][1] = LDA(As0, 3, 0);
      af[1][0] = LDA(As0, 2, 1); af[1][1] = LDA(As0, 3, 1);
      if (notlast) stB(Bs0, 2 * it + 2);
      SBAR();
      WLGKM0();
      __builtin_amdgcn_s_setprio(1);
#pragma unroll
      for (int kk = 0; kk < 2; ++kk)
#pragma unroll
        for (int i = 0; i < 2; ++i)
#pragma unroll
          for (int ni = 0; ni < 4; ++ni)
            acc[2 + i][ni] = MFMA16(af[kk][i], bf[kk][ni], acc[2 + i][ni], 0, 0, 0);
      __builtin_amdgcn_s_setprio(0);
      if (notlast) { WVM(2); } else { WVM(0); }
      SBAR();
    }
    // ---- ph2 ----
    {
      bf16x8 af[2][2];
      af[0][0] = LDA(As1, 0, 0); af[0][1] = LDA(As1, 1, 0);
      af[1][0] = LDA(As1, 0, 1); af[1][1] = LDA(As1, 1, 1);
#pragma unroll
      for (int kk = 0; kk < 2; ++kk)
#pragma unroll
        for (int ni = 0; ni < 4; ++ni) bf[kk][ni] = LDB(Bs1, ni, kk);
      if (notlast) stA(As0, 2 * it + 2);
      SBAR();
      WLGKM0();
      __builtin_amdgcn_s_setprio(1);
#pragma unroll
      for (int kk = 0; kk < 2; ++kk)
#pragma unroll
        for (int i = 0; i < 2; ++i)
#pragma unroll
          for (int ni = 0; ni < 4; ++ni)
            acc[i][ni] = MFMA16(af[kk][i], bf[kk][ni], acc[i][ni], 0, 0, 0);
      __builtin_amdgcn_s_setprio(0);
      SBAR();
    }
    // ---- ph3 ----
    {
      bf16x8 af[2][2];
      af[0][0] = LDA(As1, 2, 0); af[0][1] = LDA(As1, 3, 0);
      af[1][0] = LDA(As1, 2, 1); af[1][1] = LDA(As1, 3, 1);
      if (notlast) stB(Bs1, 2 * it + 3);
      SBAR();
      WLGKM0();
      __builtin_amdgcn_s_setprio(1);
#pragma unroll
      for (int kk = 0; kk < 2; ++kk)
#pragma unroll
        for (int i = 0; i < 2; ++i)
#pragma unroll
          for (int ni = 0; ni < 4; ++ni)
            acc[2 + i][ni] = MFMA16(af[kk][i], bf[kk][ni], acc[2 + i][ni], 0, 0, 0);
      __builtin_amdgcn_s_setprio(0);
      if (notlast) WVM(2);
      SBAR();
    }
  }

  // epilogue
  const float SCLQ = 0.125f * 1.44269504088896f;
#pragma unroll
  for (int ni = 0; ni < 4; ++ni) {
    int col = bn + wn * 64 + ni * 16 + l15;
    float bs;
    if (OUTMODE == 4)
      bs = (col < 1024) ? bias1[col] : bias2[col - 1024];
    else
      bs = bias1[col];
#pragma unroll
    for (int mi = 0; mi < 4; ++mi) {
      int row0 = bm + wm * 64 + mi * 16 + (lq << 2);
      if (OUTMODE == 2) {
        int b_ = row0 >> 11, s0 = row0 & 2047;
        unsigned short* dst = (unsigned short*)out1 +
            ((size_t)((b_ * Hh + (col >> 7)) * DVv + (col & 127))) * Ss + s0;
        ushort4 o;
        o.x = f2b(acc[mi][ni][0] + bs);
        o.y = f2b(acc[mi][ni][1] + bs);
        o.z = f2b(acc[mi][ni][2] + bs);
        o.w = f2b(acc[mi][ni][3] + bs);
        *reinterpret_cast<ushort4*>(dst) = o;
      } else if (OUTMODE == 4) {
        unsigned short* tgt = (unsigned short*)(col < 1024 ? out1 : out2);
        int cc = col & 1023, hh = cc >> 6, d = cc & 63;
#pragma unroll
        for (int r = 0; r < 4; ++r) {
          int row = row0 + r;
          int b_ = row >> 11, s0 = row & 2047;
          float v = acc[mi][ni][r] + bs;
          if (col < 1024) v *= SCLQ;  // fold softmax scale+log2e into Q
          tgt[(((size_t)(b_ * Hh + hh) * Ss + s0) << 6) + d] = f2b(v);
        }
      } else {
#pragma unroll
        for (int r = 0; r < 4; ++r)
          reinterpret_cast<float*>(out1)[(size_t)(row0 + r) * N + col] = acc[mi][ni][r] + bs;
      }
    }
  }
#undef LDA
#undef LDB
}

// ---------------------------------------------------------------------------
// Flash attention, causal, 8-wave shared-LDS staging, 32x32x16 MFMA path.
// Swapped QK (mfma(K,Q)): S^T[kv][q], lane owns q=l&31 (mate lane^32 holds the
// other 32 kv of the same row) -> softmax lane-local + ONE shfl_xor(32).
// P->PV A-operand built fully in-register: v_cvt_pk_bf16_f32 + v_permlane32_swap
// (T12; frag word order {a,c,b,d} after swap(a,b), swap(c,d) - derived & checked).
// Q is pre-scaled by 0.125*log2e in the projection. LDS 48KB (no P buffer).
// ---------------------------------------------------------------------------
__global__ __launch_bounds__(512, 1) void attn11_kernel(const unsigned short* __restrict__ Qh,
                                                        const unsigned short* __restrict__ Kh,
                                                        const unsigned short* __restrict__ Vt,
                                                        unsigned short* __restrict__ Aw) {
  __shared__ unsigned short Kb[2][64 * 64];
  __shared__ unsigned short Vb[2][128 * 64];
  const int bid = blockIdx.x;
  const int phase = bid >> 8, idx = bid & 255;
  const int xcd = idx & 7, sub = idx >> 3;
  const int bhL = sub >> 2, q = sub & 3;
  const int bh = xcd + (bhL << 3);
  const int b = bh >> 4, h = bh & 15;
  const int qt = phase ? q : 7 - q;
  const int tid = threadIdx.x, wave = tid >> 6, lane = tid & 63;
  const int l31 = lane & 31, lh = lane >> 5;

  const unsigned short* Qsrc = Qh + (size_t)(b * Hh + h) * Ss * DKk;
  const unsigned short* Ksrc = Kh + (size_t)(b * Hh + h) * Ss * DKk;
  const unsigned short* Vsrc = Vt + (size_t)(b * Hh + h) * (size_t)DVv * Ss;
  unsigned short* Adst = Aw + (size_t)b * Ss * NV + h * DVv;

  const int nt = (qt + 1) * 4;
  const int q0w = qt * 256 + wave * 32;

  const int srow = tid >> 3, sch = tid & 7;
  const int soff = ((sch ^ (srow & 7)) << 3);
  const int rx = l31 & 7;  // read-side XOR (row&7 for rows ..+l31)

  union PU { unsigned u[4]; bf16x8 v; };

  // Q fragments (B-operand): col=q=l31, k = ks*16 + lh*8 + j
  bf16x8 qf[4];
#pragma unroll
  for (int ks = 0; ks < 4; ++ks)
    qf[ks] = *reinterpret_cast<const bf16x8*>(
        Qsrc + (size_t)(q0w + l31) * DKk + ks * 16 + lh * 8);

  f32x16 accO[4] = {};  // [dvb]: row=q pattern, col=dv=dvb*32+l31
  float mrow = -1e30f, lrow = 0.f;

  {
    GLL16(Ksrc + (size_t)srow * DKk + soff, &Kb[0][(size_t)tid * 8]);
    GLL16(Vsrc + (size_t)srow * Ss + soff, &Vb[0][(size_t)tid * 8]);
    GLL16(Vsrc + (size_t)(srow + 64) * Ss + soff, &Vb[0][(size_t)(tid + 512) * 8]);
  }

  for (int kt = 0; kt < nt; ++kt) {
    const int kbase = kt * 64;
    const int cur = kt & 1;
    __syncthreads();
    if (kt + 1 < nt) {
      const int nb = kbase + 64;
      const int nxt = cur ^ 1;
      GLL16(Ksrc + (size_t)(nb + srow) * DKk + soff, &Kb[nxt][(size_t)tid * 8]);
      GLL16(Vsrc + (size_t)srow * Ss + nb + soff, &Vb[nxt][(size_t)tid * 8]);
      GLL16(Vsrc + (size_t)(srow + 64) * Ss + nb + soff, &Vb[nxt][(size_t)(tid + 512) * 8]);
    }
    if (kbase > q0w + 31) continue;

    // QK^T swapped at 32x32: accS[kvb][reg]: col=q=l31, row kv = kvb*32 + kvr(reg)
    // kvr(reg) = (reg&3) + 8*(reg>>2) + 4*lh
    f32x16 accS[2] = {};
    __builtin_amdgcn_s_setprio(1);
#pragma unroll
    for (int kvb = 0; kvb < 2; ++kvb)
#pragma unroll
      for (int ks = 0; ks < 4; ++ks) {
        const unsigned short* kr = &Kb[cur][(kvb * 32 + l31) * 64];
        bf16x8 kf = *reinterpret_cast<const bf16x8*>(kr + (((ks * 2 + lh) ^ rx) << 3));
        accS[kvb] = MFMA32(kf, qf[ks], accS[kvb], 0, 0, 0);
      }
    __builtin_amdgcn_s_setprio(0);

    // causal mask (last tile per wave only)
    if (kbase + 63 > q0w) {
      int qg = q0w + l31;
#pragma unroll
      for (int kvb = 0; kvb < 2; ++kvb)
#pragma unroll
        for (int reg = 0; reg < 16; ++reg) {
          int kvg = kbase + kvb * 32 + (reg & 3) + 8 * (reg >> 2) + 4 * lh;
          if (kvg > qg) accS[kvb][reg] = -1e30f;
        }
    }
    // row max (in-register tree + one cross-half shfl)
    float t[8];
#pragma unroll
    for (int i = 0; i < 8; ++i)
      t[i] = fmaxf(fmaxf(accS[0][i], accS[0][i + 8]), fmaxf(accS[1][i], accS[1][i + 8]));
    float pmx = fmaxf(fmaxf(fmaxf(t[0], t[1]), fmaxf(t[2], t[3])),
                      fmaxf(fmaxf(t[4], t[5]), fmaxf(t[6], t[7])));
    pmx = fmaxf(pmx, __shfl_xor(pmx, 32));
    float mn = mrow;
    if (!__all(pmx - mn <= 8.f)) {  // T13 defer-max (exp2 domain)
      float mnew = fmaxf(mn, pmx);
      float al = exp2f(mn - mnew);
      mrow = mnew;
      lrow *= al;
#pragma unroll
      for (int reg = 0; reg < 16; ++reg) {
        float a = __shfl(al, (reg & 3) + 8 * (reg >> 2) + 4 * lh);
#pragma unroll
        for (int dvb = 0; dvb < 4; ++dvb) accO[dvb][reg] *= a;
      }
      mn = mnew;
    }
    // exp + row sum (in place)
    float rs = 0.f;
#pragma unroll
    for (int kvb = 0; kvb < 2; ++kvb)
#pragma unroll
      for (int reg = 0; reg < 16; ++reg) {
        float e = exp2f(accS[kvb][reg] - mn);
        accS[kvb][reg] = e;
        rs += e;
      }
    rs += __shfl_xor(rs, 32);
    lrow += rs;
    // pack P -> A-operand frags via cvt_pk + permlane32_swap (T12)
    bf16x8 pfrag[4];
#pragma unroll
    for (int kvb = 0; kvb < 2; ++kvb)
#pragma unroll
      for (int s = 0; s < 2; ++s) {
        const int B0 = s * 8;
        unsigned a, c, bb, d;
        asm("v_cvt_pk_bf16_f32 %0, %1, %2" : "=v"(a) : "v"(accS[kvb][B0 + 0]), "v"(accS[kvb][B0 + 1]));
        asm("v_cvt_pk_bf16_f32 %0, %1, %2" : "=v"(c) : "v"(accS[kvb][B0 + 2]), "v"(accS[kvb][B0 + 3]));
        asm("v_cvt_pk_bf16_f32 %0, %1, %2" : "=v"(bb) : "v"(accS[kvb][B0 + 4]), "v"(accS[kvb][B0 + 5]));
        asm("v_cvt_pk_bf16_f32 %0, %1, %2" : "=v"(d) : "v"(accS[kvb][B0 + 6]), "v"(accS[kvb][B0 + 7]));
        asm volatile("v_permlane32_swap_b32 %0, %1" : "+v"(a), "+v"(bb));
        asm volatile("v_permlane32_swap_b32 %0, %1" : "+v"(c), "+v"(d));
        PU u;
        u.u[0] = a; u.u[1] = c; u.u[2] = bb; u.u[3] = d;
        pfrag[kvb * 2 + s] = u.v;
      }
    // PV at 32x32: accO[dvb] += P[q][kv] * V^T[kv][dv]
    __builtin_amdgcn_s_setprio(1);
#pragma unroll
    for (int dvb = 0; dvb < 4; ++dvb) {
      const unsigned short* vr = &Vb[cur][(dvb * 32 + l31) * 64];
#pragma unroll
      for (int ks = 0; ks < 4; ++ks) {
        bf16x8 vf = *reinterpret_cast<const bf16x8*>(vr + (((ks * 2 + lh) ^ rx) << 3));
        accO[dvb] = MFMA32(pfrag[ks], vf, accO[dvb], 0, 0, 0);
      }
    }
    __builtin_amdgcn_s_setprio(0);
  }
  // epilogue: normalize (lrow lane-local at q=l31 -> shfl per reg-row) + store
  float linv = 1.f / lrow;
#pragma unroll
  for (int reg = 0; reg < 16; ++reg) {
    int qr = (reg & 3) + 8 * (reg >> 2) + 4 * lh;
    float li = __shfl(linv, qr);
    int row = q0w + qr;
#pragma unroll
    for (int dvb = 0; dvb < 4; ++dvb)
      Adst[(size_t)row * NV + dvb * 32 + l31] = f2b(accO[dvb][reg] * li);
  }
}

extern "C" void kernel_launch(void* const* d_in, const int* in_sizes, int n_in,
                              void* d_out, int out_size, void* d_ws, size_t ws_size,
                              hipStream_t stream) {
  (void)in_sizes; (void)n_in; (void)out_size; (void)ws_size;
  const float* x  = (const float*)d_in[0];
  const float* Wq = (const float*)d_in[1];
  const float* bq = (const float*)d_in[2];
  const float* Wk = (const float*)d_in[3];
  const float* bk = (const float*)d_in[4];
  const float* Wv = (const float*)d_in[5];
  const float* bv = (const float*)d_in[6];
  const float* Wo = (const float*)d_in[7];
  const float* bo = (const float*)d_in[8];
  float* out = (float*)d_out;

  unsigned short* ws = (unsigned short*)d_ws;
  unsigned short* xb  = ws;                    // 8388608  (x bf16 [8192][1024])
  unsigned short* WqT = xb  + 8388608;         // 1048576  ([H*DK][E])   } contiguous ->
  unsigned short* WkT = WqT + 1048576;         // 1048576  ([H*DK][E])   } fused QK BT [2048][1024]
  unsigned short* WvT = WkT + 1048576;         // 2097152  ([H*DV][E])
  unsigned short* WoT = WvT + 2097152;         // 2097152  ([E][H*DV])
  unsigned short* Qw  = WoT + 2097152;         // 8388608  ([B,H,S,64], pre-scaled)
  unsigned short* Kw  = Qw  + 8388608;         // 8388608  ([B,H,S,64])
  unsigned short* Vtw = Kw  + 8388608;         // 16777216 ([B,H,128,S])
  unsigned short* Aw  = Vtw + 16777216;        // 16777216 ([B,S,H*DV])

  cast_x_kernel<<<dim3(8192), dim3(256), 0, stream>>>(x, xb, (Mm * Ee) / 4);

  transpose_cast_kernel<<<dim3(2, 32, 16), dim3(32, 8), 0, stream>>>(Wq, WqT, Ee, DKk);
  transpose_cast_kernel<<<dim3(2, 32, 16), dim3(32, 8), 0, stream>>>(Wk, WkT, Ee, DKk);
  transpose_cast_kernel<<<dim3(4, 32, 16), dim3(32, 8), 0, stream>>>(Wv, WvT, Ee, DVv);
  transpose_cast_kernel<<<dim3(32, 64, 1), dim3(32, 8), 0, stream>>>(Wo, WoT, NV, Ee);

  // fused Q+K projection: N=2048 (grid 512), Q pre-scaled by 0.125*log2e
  gemm8_kernel<4><<<dim3(512), dim3(512), 0, stream>>>(xb, WqT, bq, bk, Qw, Kw, 2048, Ee);
  // V projection -> Vt[B,H,DV,S]
  gemm8_kernel<2><<<dim3(512), dim3(512), 0, stream>>>(xb, WvT, bv, nullptr, Vtw, nullptr, NV, Ee);

  attn11_kernel<<<dim3(512), dim3(512), 0, stream>>>(Qw, Kw, Vtw, Aw);

  // output projection: f32 out, K=2048
  gemm8_kernel<1><<<dim3(256), dim3(512), 0, stream>>>(Aw, WoT, bo, nullptr, out, nullptr, NQ, NV);
}

// Round 14
// 282.396 us; speedup vs baseline: 3.9055x; 1.0847x over previous
//
#include <hip/hip_runtime.h>

typedef __bf16 bf16x8 __attribute__((ext_vector_type(8)));
typedef float f32x4 __attribute__((ext_vector_type(4)));
typedef float f32x16 __attribute__((ext_vector_type(16)));

static constexpr int Bb = 4, Ss = 2048, Ee = 1024, Hh = 16, DKk = 64, DVv = 128;
static constexpr int Mm = Bb * Ss;   // 8192
static constexpr int NQ = Hh * DKk;  // 1024
static constexpr int NV = Hh * DVv;  // 2048

#define MFMA16 __builtin_amdgcn_mfma_f32_16x16x32_bf16
#define MFMA32 __builtin_amdgcn_mfma_f32_32x32x16_bf16

#define GLL16(g, l) __builtin_amdgcn_global_load_lds(                        \
    (const __attribute__((address_space(1))) void*)(g),                      \
    (__attribute__((address_space(3))) void*)(l), 16, 0, 0)

#define SBAR()   asm volatile("s_barrier" ::: "memory")
#define WLGKM0() do { asm volatile("s_waitcnt lgkmcnt(0)" ::: "memory"); \
                      __builtin_amdgcn_sched_barrier(0); } while (0)
#define WVM(n)   asm volatile("s_waitcnt vmcnt(" #n ")" ::: "memory")

static __device__ __forceinline__ unsigned short f2b(float f) {
  unsigned int u = __float_as_uint(f);
  u += 0x7fffu + ((u >> 16) & 1u);
  return (unsigned short)(u >> 16);
}

__global__ __launch_bounds__(256) void cast_x_kernel(const float* __restrict__ in,
                                                     unsigned short* __restrict__ out, int n4) {
  int i = blockIdx.x * 256 + threadIdx.x;
  if (i >= n4) return;
  float4 v = reinterpret_cast<const float4*>(in)[i];
  ushort4 o;
  o.x = f2b(v.x); o.y = f2b(v.y); o.z = f2b(v.z); o.w = f2b(v.w);
  reinterpret_cast<ushort4*>(out)[i] = o;
}

// in: [Bt][R][C] f32  ->  out: [Bt][C][R] bf16
__global__ __launch_bounds__(256) void transpose_cast_kernel(const float* __restrict__ in,
                                                             unsigned short* __restrict__ out,
                                                             int R, int C) {
  __shared__ float tile[32][33];
  int c0 = blockIdx.x * 32, r0 = blockIdx.y * 32;
  const float* ip = in + (size_t)blockIdx.z * R * C;
  unsigned short* op = out + (size_t)blockIdx.z * R * C;
  int tx = threadIdx.x, ty = threadIdx.y;
#pragma unroll
  for (int i = 0; i < 32; i += 8)
    tile[ty + i][tx] = ip[(size_t)(r0 + ty + i) * C + (c0 + tx)];
  __syncthreads();
#pragma unroll
  for (int i = 0; i < 32; i += 8)
    op[(size_t)(c0 + ty + i) * R + (r0 + tx)] = f2b(tile[tx][ty + i]);
}

// ---------------------------------------------------------------------------
// gemm9: 256x256-tile phase-pipelined GEMM (scaled gemm8 choreography).
// BM=256, BN=256, BK=64; 512 thr / 8 waves (2M x 4N), per-wave 128x64 (acc 8x4).
// 2 K-tiles/iter, 4 phases x 32 MFMA. Counted vmcnt(4), raw s_barrier, setprio,
// both-sides XOR swizzle. LDS 128KB (As0/As1/Bs0/Bs1 each 256x64).
// Ledger: ph1-end out = prevBs1(4)+As1(4)+Bs0(4) -> WVM(4) completes prevBs1+As1;
// ph3-end out = Bs0(4)+As0(4)+Bs1(4) -> WVM(4) completes Bs0+As0 for next ph0.
// Every stage lands >=1 barrier after its buffer's last read. Last iter: WVM(0)@ph1.
// OUTMODE: 2 = bf16 Vt[B,H,DV,S]; 4 = fused QK head-major, Q pre-scaled.
// ---------------------------------------------------------------------------
template <int OUTMODE>
__global__ __launch_bounds__(512, 2) void gemm9_kernel(const unsigned short* __restrict__ A,
                                                       const unsigned short* __restrict__ BT,
                                                       const float* __restrict__ bias1,
                                                       const float* __restrict__ bias2,
                                                       void* __restrict__ out1,
                                                       void* __restrict__ out2,
                                                       int N, int K) {
  __shared__ unsigned short As0[256 * 64], As1[256 * 64];
  __shared__ unsigned short Bs0[256 * 64], Bs1[256 * 64];
  const int tid = threadIdx.x, wave = tid >> 6, lane = tid & 63;
  const int wm = wave >> 2, wn = wave & 3;
  const int l15 = lane & 15, lq = lane >> 4;
  const int nwg = gridDim.x, cpx = nwg >> 3;
  const int orig = (blockIdx.x & 7) * cpx + (blockIdx.x >> 3);  // XCD-contiguous
  const int bm = (orig & 31) << 8, bn = (orig >> 5) << 8;
  const int srow = tid >> 3;
  const int ssw = (((tid & 7) ^ (srow & 7)) << 3);  // pre-swizzled source offset
  const int rsw = l15 & 7;                          // read-side XOR
  const int nIter = K >> 7;

  f32x4 acc[8][4] = {};
  bf16x8 bf[2][4];

#define LDA9(ASQ, MI, KK) \
  (*reinterpret_cast<const bf16x8*>(&(ASQ)[(size_t)((wm * 128 + (MI)*16 + l15) * 64) + (((((KK)*4 + lq)) ^ rsw) << 3)]))
#define LDB9(BSQ, NI, KK) \
  (*reinterpret_cast<const bf16x8*>(&(BSQ)[(size_t)((wn * 64 + (NI)*16 + l15) * 64) + (((((KK)*4 + lq)) ^ rsw) << 3)]))

  auto stA = [&](unsigned short* dst, int kt) {
#pragma unroll
    for (int k4 = 0; k4 < 4; ++k4)
      GLL16(A + (size_t)(bm + srow + k4 * 64) * K + kt * 64 + ssw,
            &dst[(size_t)(tid + k4 * 512) * 8]);
  };
  auto stB = [&](unsigned short* dst, int kt) {
#pragma unroll
    for (int k4 = 0; k4 < 4; ++k4)
      GLL16(BT + (size_t)(bn + srow + k4 * 64) * K + kt * 64 + ssw,
            &dst[(size_t)(tid + k4 * 512) * 8]);
  };

  stA(As0, 0);
  stB(Bs0, 0);
  stB(Bs1, 1);
  WVM(0);
  SBAR();

  for (int it = 0; it < nIter; ++it) {
    const bool notlast = (it < nIter - 1);
    // ---- ph0: t0, mi 0-3 ----
    {
      bf16x8 af[2][4];
#pragma unroll
      for (int kk = 0; kk < 2; ++kk)
#pragma unroll
        for (int m = 0; m < 4; ++m) af[kk][m] = LDA9(As0, m, kk);
#pragma unroll
      for (int kk = 0; kk < 2; ++kk)
#pragma unroll
        for (int ni = 0; ni < 4; ++ni) bf[kk][ni] = LDB9(Bs0, ni, kk);
      stA(As1, 2 * it + 1);  // ALWAYS (it=0 too)
      SBAR();
      WLGKM0();
      __builtin_amdgcn_s_setprio(1);
#pragma unroll
      for (int kk = 0; kk < 2; ++kk)
#pragma unroll
        for (int m = 0; m < 4; ++m)
#pragma unroll
          for (int ni = 0; ni < 4; ++ni)
            acc[m][ni] = MFMA16(af[kk][m], bf[kk][ni], acc[m][ni], 0, 0, 0);
      __builtin_amdgcn_s_setprio(0);
      SBAR();
    }
    // ---- ph1: t0, mi 4-7 ----
    {
      bf16x8 af[2][4];
#pragma unroll
      for (int kk = 0; kk < 2; ++kk)
#pragma unroll
        for (int m = 0; m < 4; ++m) af[kk][m] = LDA9(As0, 4 + m, kk);
      if (notlast) stB(Bs0, 2 * it + 2);
      SBAR();
      WLGKM0();
      __builtin_amdgcn_s_setprio(1);
#pragma unroll
      for (int kk = 0; kk < 2; ++kk)
#pragma unroll
        for (int m = 0; m < 4; ++m)
#pragma unroll
          for (int ni = 0; ni < 4; ++ni)
            acc[4 + m][ni] = MFMA16(af[kk][m], bf[kk][ni], acc[4 + m][ni], 0, 0, 0);
      __builtin_amdgcn_s_setprio(0);
      if (notlast) { WVM(4); } else { WVM(0); }
      SBAR();
    }
    // ---- ph2: t1, mi 0-3 ----
    {
      bf16x8 af[2][4];
#pragma unroll
      for (int kk = 0; kk < 2; ++kk)
#pragma unroll
        for (int m = 0; m < 4; ++m) af[kk][m] = LDA9(As1, m, kk);
#pragma unroll
      for (int kk = 0; kk < 2; ++kk)
#pragma unroll
        for (int ni = 0; ni < 4; ++ni) bf[kk][ni] = LDB9(Bs1, ni, kk);
      if (notlast) stA(As0, 2 * it + 2);
      SBAR();
      WLGKM0();
      __builtin_amdgcn_s_setprio(1);
#pragma unroll
      for (int kk = 0; kk < 2; ++kk)
#pragma unroll
        for (int m = 0; m < 4; ++m)
#pragma unroll
          for (int ni = 0; ni < 4; ++ni)
            acc[m][ni] = MFMA16(af[kk][m], bf[kk][ni], acc[m][ni], 0, 0, 0);
      __builtin_amdgcn_s_setprio(0);
      SBAR();
    }
    // ---- ph3: t1, mi 4-7 ----
    {
      bf16x8 af[2][4];
#pragma unroll
      for (int kk = 0; kk < 2; ++kk)
#pragma unroll
        for (int m = 0; m < 4; ++m) af[kk][m] = LDA9(As1, 4 + m, kk);
      if (notlast) stB(Bs1, 2 * it + 3);
      SBAR();
      WLGKM0();
      __builtin_amdgcn_s_setprio(1);
#pragma unroll
      for (int kk = 0; kk < 2; ++kk)
#pragma unroll
        for (int m = 0; m < 4; ++m)
#pragma unroll
          for (int ni = 0; ni < 4; ++ni)
            acc[4 + m][ni] = MFMA16(af[kk][m], bf[kk][ni], acc[4 + m][ni], 0, 0, 0);
      __builtin_amdgcn_s_setprio(0);
      if (notlast) WVM(4);
      SBAR();
    }
  }

  // epilogue
  const float SCLQ = 0.125f * 1.44269504088896f;
#pragma unroll
  for (int ni = 0; ni < 4; ++ni) {
    int col = bn + wn * 64 + ni * 16 + l15;
    float bs;
    if (OUTMODE == 4)
      bs = (col < 1024) ? bias1[col] : bias2[col - 1024];
    else
      bs = bias1[col];
#pragma unroll
    for (int mi = 0; mi < 8; ++mi) {
      int row0 = bm + wm * 128 + mi * 16 + (lq << 2);
      if (OUTMODE == 2) {
        int b_ = row0 >> 11, s0 = row0 & 2047;
        unsigned short* dst = (unsigned short*)out1 +
            ((size_t)((b_ * Hh + (col >> 7)) * DVv + (col & 127))) * Ss + s0;
        ushort4 o;
        o.x = f2b(acc[mi][ni][0] + bs);
        o.y = f2b(acc[mi][ni][1] + bs);
        o.z = f2b(acc[mi][ni][2] + bs);
        o.w = f2b(acc[mi][ni][3] + bs);
        *reinterpret_cast<ushort4*>(dst) = o;
      } else {  // OUTMODE == 4
        unsigned short* tgt = (unsigned short*)(col < 1024 ? out1 : out2);
        int cc = col & 1023, hh = cc >> 6, d = cc & 63;
#pragma unroll
        for (int r = 0; r < 4; ++r) {
          int row = row0 + r;
          int b_ = row >> 11, s0 = row & 2047;
          float v = acc[mi][ni][r] + bs;
          if (col < 1024) v *= SCLQ;  // fold softmax scale+log2e into Q
          tgt[(((size_t)(b_ * Hh + hh) * Ss + s0) << 6) + d] = f2b(v);
        }
      }
    }
  }
#undef LDA9
#undef LDB9
}

// ---------------------------------------------------------------------------
// gemm8 (round-11, proven): BM=256,BN=128 — used for out-proj (N=1024 -> 256 blocks).
// OUTMODE 1 = f32 [M][N].
// ---------------------------------------------------------------------------
__global__ __launch_bounds__(512, 2) void gemm8f_kernel(const unsigned short* __restrict__ A,
                                                        const unsigned short* __restrict__ BT,
                                                        const float* __restrict__ bias1,
                                                        float* __restrict__ out1,
                                                        int N, int K) {
  __shared__ unsigned short As0[256 * 64], As1[256 * 64];
  __shared__ unsigned short Bs0[128 * 64], Bs1[128 * 64];
  const int tid = threadIdx.x, wave = tid >> 6, lane = tid & 63;
  const int wm = wave >> 1, wn = wave & 1;
  const int l15 = lane & 15, lq = lane >> 4;
  const int nwg = gridDim.x, cpx = nwg >> 3;
  const int orig = (blockIdx.x & 7) * cpx + (blockIdx.x >> 3);
  const int bm = (orig & 31) << 8, bn = (orig >> 5) << 7;
  const int srow = tid >> 3;
  const int ssw = (((tid & 7) ^ (srow & 7)) << 3);
  const int rsw = l15 & 7;
  const int nIter = K >> 7;

  f32x4 acc[4][4] = {};
  bf16x8 bf[2][4];

#define LDA(ASQ, MI, KK) \
  (*reinterpret_cast<const bf16x8*>(&(ASQ)[(size_t)((wm * 64 + (MI)*16 + l15) * 64) + (((((KK)*4 + lq)) ^ rsw) << 3)]))
#define LDB(BSQ, NI, KK) \
  (*reinterpret_cast<const bf16x8*>(&(BSQ)[(size_t)((wn * 64 + (NI)*16 + l15) * 64) + (((((KK)*4 + lq)) ^ rsw) << 3)]))

  auto stA = [&](unsigned short* dst, int kt) {
#pragma unroll
    for (int k4 = 0; k4 < 4; ++k4)
      GLL16(A + (size_t)(bm + srow + k4 * 64) * K + kt * 64 + ssw,
            &dst[(size_t)(tid + k4 * 512) * 8]);
  };
  auto stB = [&](unsigned short* dst, int kt) {
#pragma unroll
    for (int k4 = 0; k4 < 2; ++k4)
      GLL16(BT + (size_t)(bn + srow + k4 * 64) * K + kt * 64 + ssw,
            &dst[(size_t)(tid + k4 * 512) * 8]);
  };

  stA(As0, 0);
  stB(Bs0, 0);
  stB(Bs1, 1);
  WVM(0);
  SBAR();

  for (int it = 0; it < nIter; ++it) {
    const bool notlast = (it < nIter - 1);
    {
      bf16x8 af[2][2];
      af[0][0] = LDA(As0, 0, 0); af[0][1] = LDA(As0, 1, 0);
      af[1][0] = LDA(As0, 0, 1); af[1][1] = LDA(As0, 1, 1);
#pragma unroll
      for (int kk = 0; kk < 2; ++kk)
#pragma unroll
        for (int ni = 0; ni < 4; ++ni) bf[kk][ni] = LDB(Bs0, ni, kk);
      stA(As1, 2 * it + 1);
      SBAR();
      WLGKM0();
      __builtin_amdgcn_s_setprio(1);
#pragma unroll
      for (int kk = 0; kk < 2; ++kk)
#pragma unroll
        for (int i = 0; i < 2; ++i)
#pragma unroll
          for (int ni = 0; ni < 4; ++ni)
            acc[i][ni] = MFMA16(af[kk][i], bf[kk][ni], acc[i][ni], 0, 0, 0);
      __builtin_amdgcn_s_setprio(0);
      SBAR();
    }
    {
      bf16x8 af[2][2];
      af[0][0] = LDA(As0, 2, 0); af[0][1] = LDA(As0, 3, 0);
      af[1][0] = LDA(As0, 2, 1); af[1][1] = LDA(As0, 3, 1);
      if (notlast) stB(Bs0, 2 * it + 2);
      SBAR();
      WLGKM0();
      __builtin_amdgcn_s_setprio(1);
#pragma unroll
      for (int kk = 0; kk < 2; ++kk)
#pragma unroll
        for (int i = 0; i < 2; ++i)
#pragma unroll
          for (int ni = 0; ni < 4; ++ni)
            acc[2 + i][ni] = MFMA16(af[kk][i], bf[kk][ni], acc[2 + i][ni], 0, 0, 0);
      __builtin_amdgcn_s_setprio(0);
      if (notlast) { WVM(2); } else { WVM(0); }
      SBAR();
    }
    {
      bf16x8 af[2][2];
      af[0][0] = LDA(As1, 0, 0); af[0][1] = LDA(As1, 1, 0);
      af[1][0] = LDA(As1, 0, 1); af[1][1] = LDA(As1, 1, 1);
#pragma unroll
      for (int kk = 0; kk < 2; ++kk)
#pragma unroll
        for (int ni = 0; ni < 4; ++ni) bf[kk][ni] = LDB(Bs1, ni, kk);
      if (notlast) stA(As0, 2 * it + 2);
      SBAR();
      WLGKM0();
      __builtin_amdgcn_s_setprio(1);
#pragma unroll
      for (int kk = 0; kk < 2; ++kk)
#pragma unroll
        for (int i = 0; i < 2; ++i)
#pragma unroll
          for (int ni = 0; ni < 4; ++ni)
            acc[i][ni] = MFMA16(af[kk][i], bf[kk][ni], acc[i][ni], 0, 0, 0);
      __builtin_amdgcn_s_setprio(0);
      SBAR();
    }
    {
      bf16x8 af[2][2];
      af[0][0] = LDA(As1, 2, 0); af[0][1] = LDA(As1, 3, 0);
      af[1][0] = LDA(As1, 2, 1); af[1][1] = LDA(As1, 3, 1);
      if (notlast) stB(Bs1, 2 * it + 3);
      SBAR();
      WLGKM0();
      __builtin_amdgcn_s_setprio(1);
#pragma unroll
      for (int kk = 0; kk < 2; ++kk)
#pragma unroll
        for (int i = 0; i < 2; ++i)
#pragma unroll
          for (int ni = 0; ni < 4; ++ni)
            acc[2 + i][ni] = MFMA16(af[kk][i], bf[kk][ni], acc[2 + i][ni], 0, 0, 0);
      __builtin_amdgcn_s_setprio(0);
      if (notlast) WVM(2);
      SBAR();
    }
  }

#pragma unroll
  for (int ni = 0; ni < 4; ++ni) {
    int col = bn + wn * 64 + ni * 16 + l15;
    float bs = bias1[col];
#pragma unroll
    for (int mi = 0; mi < 4; ++mi) {
      int row0 = bm + wm * 64 + mi * 16 + (lq << 2);
#pragma unroll
      for (int r = 0; r < 4; ++r)
        out1[(size_t)(row0 + r) * N + col] = acc[mi][ni][r] + bs;
    }
  }
#undef LDA
#undef LDB
}

// Flash attention (round-13, unchanged): 32x32 MFMA, T12 in-register P, 139 us.
__global__ __launch_bounds__(512, 1) void attn11_kernel(const unsigned short* __restrict__ Qh,
                                                        const unsigned short* __restrict__ Kh,
                                                        const unsigned short* __restrict__ Vt,
                                                        unsigned short* __restrict__ Aw) {
  __shared__ unsigned short Kb[2][64 * 64];
  __shared__ unsigned short Vb[2][128 * 64];
  const int bid = blockIdx.x;
  const int phase = bid >> 8, idx = bid & 255;
  const int xcd = idx & 7, sub = idx >> 3;
  const int bhL = sub >> 2, q = sub & 3;
  const int bh = xcd + (bhL << 3);
  const int b = bh >> 4, h = bh & 15;
  const int qt = phase ? q : 7 - q;
  const int tid = threadIdx.x, wave = tid >> 6, lane = tid & 63;
  const int l31 = lane & 31, lh = lane >> 5;

  const unsigned short* Qsrc = Qh + (size_t)(b * Hh + h) * Ss * DKk;
  const unsigned short* Ksrc = Kh + (size_t)(b * Hh + h) * Ss * DKk;
  const unsigned short* Vsrc = Vt + (size_t)(b * Hh + h) * (size_t)DVv * Ss;
  unsigned short* Adst = Aw + (size_t)b * Ss * NV + h * DVv;

  const int nt = (qt + 1) * 4;
  const int q0w = qt * 256 + wave * 32;

  const int srow = tid >> 3, sch = tid & 7;
  const int soff = ((sch ^ (srow & 7)) << 3);
  const int rx = l31 & 7;

  union PU { unsigned u[4]; bf16x8 v; };

  bf16x8 qf[4];
#pragma unroll
  for (int ks = 0; ks < 4; ++ks)
    qf[ks] = *reinterpret_cast<const bf16x8*>(
        Qsrc + (size_t)(q0w + l31) * DKk + ks * 16 + lh * 8);

  f32x16 accO[4] = {};
  float mrow = -1e30f, lrow = 0.f;

  {
    GLL16(Ksrc + (size_t)srow * DKk + soff, &Kb[0][(size_t)tid * 8]);
    GLL16(Vsrc + (size_t)srow * Ss + soff, &Vb[0][(size_t)tid * 8]);
    GLL16(Vsrc + (size_t)(srow + 64) * Ss + soff, &Vb[0][(size_t)(tid + 512) * 8]);
  }

  for (int kt = 0; kt < nt; ++kt) {
    const int kbase = kt * 64;
    const int cur = kt & 1;
    __syncthreads();
    if (kt + 1 < nt) {
      const int nb = kbase + 64;
      const int nxt = cur ^ 1;
      GLL16(Ksrc + (size_t)(nb + srow) * DKk + soff, &Kb[nxt][(size_t)tid * 8]);
      GLL16(Vsrc + (size_t)srow * Ss + nb + soff, &Vb[nxt][(size_t)tid * 8]);
      GLL16(Vsrc + (size_t)(srow + 64) * Ss + nb + soff, &Vb[nxt][(size_t)(tid + 512) * 8]);
    }
    if (kbase > q0w + 31) continue;

    f32x16 accS[2] = {};
    __builtin_amdgcn_s_setprio(1);
#pragma unroll
    for (int kvb = 0; kvb < 2; ++kvb)
#pragma unroll
      for (int ks = 0; ks < 4; ++ks) {
        const unsigned short* kr = &Kb[cur][(kvb * 32 + l31) * 64];
        bf16x8 kf = *reinterpret_cast<const bf16x8*>(kr + (((ks * 2 + lh) ^ rx) << 3));
        accS[kvb] = MFMA32(kf, qf[ks], accS[kvb], 0, 0, 0);
      }
    __builtin_amdgcn_s_setprio(0);

    if (kbase + 63 > q0w) {
      int qg = q0w + l31;
#pragma unroll
      for (int kvb = 0; kvb < 2; ++kvb)
#pragma unroll
        for (int reg = 0; reg < 16; ++reg) {
          int kvg = kbase + kvb * 32 + (reg & 3) + 8 * (reg >> 2) + 4 * lh;
          if (kvg > qg) accS[kvb][reg] = -1e30f;
        }
    }
    float t[8];
#pragma unroll
    for (int i = 0; i < 8; ++i)
      t[i] = fmaxf(fmaxf(accS[0][i], accS[0][i + 8]), fmaxf(accS[1][i], accS[1][i + 8]));
    float pmx = fmaxf(fmaxf(fmaxf(t[0], t[1]), fmaxf(t[2], t[3])),
                      fmaxf(fmaxf(t[4], t[5]), fmaxf(t[6], t[7])));
    pmx = fmaxf(pmx, __shfl_xor(pmx, 32));
    float mn = mrow;
    if (!__all(pmx - mn <= 8.f)) {
      float mnew = fmaxf(mn, pmx);
      float al = exp2f(mn - mnew);
      mrow = mnew;
      lrow *= al;
#pragma unroll
      for (int reg = 0; reg < 16; ++reg) {
        float a = __shfl(al, (reg & 3) + 8 * (reg >> 2) + 4 * lh);
#pragma unroll
        for (int dvb = 0; dvb < 4; ++dvb) accO[dvb][reg] *= a;
      }
      mn = mnew;
    }
    float rs = 0.f;
#pragma unroll
    for (int kvb = 0; kvb < 2; ++kvb)
#pragma unroll
      for (int reg = 0; reg < 16; ++reg) {
        float e = exp2f(accS[kvb][reg] - mn);
        accS[kvb][reg] = e;
        rs += e;
      }
    rs += __shfl_xor(rs, 32);
    lrow += rs;
    bf16x8 pfrag[4];
#pragma unroll
    for (int kvb = 0; kvb < 2; ++kvb)
#pragma unroll
      for (int s = 0; s < 2; ++s) {
        const int B0 = s * 8;
        unsigned a, c, bb, d;
        asm("v_cvt_pk_bf16_f32 %0, %1, %2" : "=v"(a) : "v"(accS[kvb][B0 + 0]), "v"(accS[kvb][B0 + 1]));
        asm("v_cvt_pk_bf16_f32 %0, %1, %2" : "=v"(c) : "v"(accS[kvb][B0 + 2]), "v"(accS[kvb][B0 + 3]));
        asm("v_cvt_pk_bf16_f32 %0, %1, %2" : "=v"(bb) : "v"(accS[kvb][B0 + 4]), "v"(accS[kvb][B0 + 5]));
        asm("v_cvt_pk_bf16_f32 %0, %1, %2" : "=v"(d) : "v"(accS[kvb][B0 + 6]), "v"(accS[kvb][B0 + 7]));
        asm volatile("v_permlane32_swap_b32 %0, %1" : "+v"(a), "+v"(bb));
        asm volatile("v_permlane32_swap_b32 %0, %1" : "+v"(c), "+v"(d));
        PU u;
        u.u[0] = a; u.u[1] = c; u.u[2] = bb; u.u[3] = d;
        pfrag[kvb * 2 + s] = u.v;
      }
    __builtin_amdgcn_s_setprio(1);
#pragma unroll
    for (int dvb = 0; dvb < 4; ++dvb) {
      const unsigned short* vr = &Vb[cur][(dvb * 32 + l31) * 64];
#pragma unroll
      for (int ks = 0; ks < 4; ++ks) {
        bf16x8 vf = *reinterpret_cast<const bf16x8*>(vr + (((ks * 2 + lh) ^ rx) << 3));
        accO[dvb] = MFMA32(pfrag[ks], vf, accO[dvb], 0, 0, 0);
      }
    }
    __builtin_amdgcn_s_setprio(0);
  }
  float linv = 1.f / lrow;
#pragma unroll
  for (int reg = 0; reg < 16; ++reg) {
    int qr = (reg & 3) + 8 * (reg >> 2) + 4 * lh;
    float li = __shfl(linv, qr);
    int row = q0w + qr;
#pragma unroll
    for (int dvb = 0; dvb < 4; ++dvb)
      Adst[(size_t)row * NV + dvb * 32 + l31] = f2b(accO[dvb][reg] * li);
  }
}

extern "C" void kernel_launch(void* const* d_in, const int* in_sizes, int n_in,
                              void* d_out, int out_size, void* d_ws, size_t ws_size,
                              hipStream_t stream) {
  (void)in_sizes; (void)n_in; (void)out_size; (void)ws_size;
  const float* x  = (const float*)d_in[0];
  const float* Wq = (const float*)d_in[1];
  const float* bq = (const float*)d_in[2];
  const float* Wk = (const float*)d_in[3];
  const float* bk = (const float*)d_in[4];
  const float* Wv = (const float*)d_in[5];
  const float* bv = (const float*)d_in[6];
  const float* Wo = (const float*)d_in[7];
  const float* bo = (const float*)d_in[8];
  float* out = (float*)d_out;

  unsigned short* ws = (unsigned short*)d_ws;
  unsigned short* xb  = ws;                    // 8388608  (x bf16 [8192][1024])
  unsigned short* WqT = xb  + 8388608;         // 1048576  ([H*DK][E])   } contiguous ->
  unsigned short* WkT = WqT + 1048576;         // 1048576  ([H*DK][E])   } fused QK BT [2048][1024]
  unsigned short* WvT = WkT + 1048576;         // 2097152  ([H*DV][E])
  unsigned short* WoT = WvT + 2097152;         // 2097152  ([E][H*DV])
  unsigned short* Qw  = WoT + 2097152;         // 8388608  ([B,H,S,64], pre-scaled)
  unsigned short* Kw  = Qw  + 8388608;         // 8388608  ([B,H,S,64])
  unsigned short* Vtw = Kw  + 8388608;         // 16777216 ([B,H,128,S])
  unsigned short* Aw  = Vtw + 16777216;        // 16777216 ([B,S,H*DV])

  cast_x_kernel<<<dim3(8192), dim3(256), 0, stream>>>(x, xb, (Mm * Ee) / 4);

  transpose_cast_kernel<<<dim3(2, 32, 16), dim3(32, 8), 0, stream>>>(Wq, WqT, Ee, DKk);
  transpose_cast_kernel<<<dim3(2, 32, 16), dim3(32, 8), 0, stream>>>(Wk, WkT, Ee, DKk);
  transpose_cast_kernel<<<dim3(4, 32, 16), dim3(32, 8), 0, stream>>>(Wv, WvT, Ee, DVv);
  transpose_cast_kernel<<<dim3(32, 64, 1), dim3(32, 8), 0, stream>>>(Wo, WoT, NV, Ee);

  // fused Q+K projection: 256x256 tiles, grid 32x8=256, Q pre-scaled by 0.125*log2e
  gemm9_kernel<4><<<dim3(256), dim3(512), 0, stream>>>(xb, WqT, bq, bk, Qw, Kw, 2048, Ee);
  // V projection -> Vt[B,H,DV,S], 256x256 tiles
  gemm9_kernel<2><<<dim3(256), dim3(512), 0, stream>>>(xb, WvT, bv, nullptr, Vtw, nullptr, NV, Ee);

  attn11_kernel<<<dim3(512), dim3(512), 0, stream>>>(Qw, Kw, Vtw, Aw);

  // output projection: f32 out, K=2048, BM256xBN128 (grid 256)
  gemm8f_kernel<<<dim3(256), dim3(512), 0, stream>>>(Aw, WoT, bo, out, NQ, NV);
}